// Round 5
// baseline (264.940 us; speedup 1.0000x reference)
//
#include <hip/hip_runtime.h>
#include <hip/hip_bf16.h>
#include <math.h>

#define N_NODES 8192
#define N_EDGES 131072
#define NGRP 16
#define NLAY 2
#define NELM 4
constexpr float INV_AVG = 1.0f / 16.0f;
constexpr float PI_F = 3.14159265358979323846f;

// converted fp32 buffer layout (element offsets).
#define CV_POS   0        // 24576
#define CV_EMB   24576    // 256
#define CV_SC    42240    // 32768 (natural [l][ty][c:64][d:64])
#define CV_PROD  75008    // 32
#define CV_RO0   75040    // 64
#define CV_RO1A  75104    // 1024
#define CV_RO1B  76128    // 16
#define CVT_N    76144

// swizzled bf16 MFMA B-fragment weight buffer: per layer 10240 shorts
#define SWZ_PER_L 10240
#define SWZ_N     20480

// setup1 fused-dispatch block ranges
#define B_CVT  230
#define B_SWZ  80
#define B_HIST 512
#define CVT_WORK 58736

typedef __hip_bfloat16 bf16;
typedef __attribute__((ext_vector_type(8))) short bf16x8;
typedef __attribute__((ext_vector_type(4))) float f32x4;

__device__ __forceinline__ float silu_f(float x){ return x / (1.0f + __expf(-x)); }
__device__ __forceinline__ float bfbits2f(unsigned short u){
  return __uint_as_float(((unsigned)u) << 16);
}
__device__ __forceinline__ void unpack2(unsigned u, float& lo, float& hi){
  lo = __uint_as_float(u << 16);
  hi = __uint_as_float(u & 0xffff0000u);
}
__device__ __forceinline__ short f2bs(float v){
  union { bf16 b; short s; } u; u.b = __float2bfloat16(v); return u.s;
}
__device__ __forceinline__ float ldf(const void* p, int i, int flag){
  if (flag) return bfbits2f(((const unsigned short*)p)[i]);
  return ((const float*)p)[i];
}
// per-wave input dtype detection (reads first 128 ushorts of pos; L1/L2-hot).
__device__ __forceinline__ int detect_fl(const void* pos){
  int lane = threadIdx.x & 63;
  const unsigned short* u = (const unsigned short*)pos;
  float va = bfbits2f(u[2*lane]), vb = bfbits2f(u[2*lane+1]);
  bool bad = !(fabsf(va) <= 1000.0f) || !(fabsf(vb) <= 1000.0f);
  return (__ballot(bad) == 0ull) ? 1 : 0;
}
__device__ __forceinline__ void WSYNC(){ __builtin_amdgcn_wave_barrier(); }

// async global->LDS DMA: data never touches VGPRs. LDS dest wave-uniform,
// +lane*size implicit; global src per-lane.
__device__ __forceinline__ void gl_lds4(const void* g, void* l){
  __builtin_amdgcn_global_load_lds(
      (const __attribute__((address_space(1))) unsigned*)g,
      (__attribute__((address_space(3))) unsigned*)l, 4, 0, 0);
}

// ============ S1: fused {detect, cvt, weight-swizzle, degree-hist} ============
__global__ void k_setup1(const void* __restrict__ pos, const void* __restrict__ Wemb,
                         const void* __restrict__ Wsc, const void* __restrict__ wprod,
                         const void* __restrict__ wro0, const void* __restrict__ Wro1a,
                         const void* __restrict__ wro1b, const void* __restrict__ Wr1,
                         const void* __restrict__ Wr2, const void* __restrict__ Wr3,
                         const int* __restrict__ dstp, float* __restrict__ cv,
                         short* __restrict__ swz, int* __restrict__ deg){
  int b = blockIdx.x, tix = threadIdx.x;
  if (b >= B_CVT + B_SWZ){            // ---- degree histogram ----
    int e = (b - B_CVT - B_SWZ)*256 + tix;
    atomicAdd(&deg[dstp[e]], 1);
    return;
  }
  int fl = detect_fl(pos);
  if (b < B_CVT){                      // ---- fp32 conversion ----
    int i = b*256 + tix;
    if (i < 24576){ cv[CV_POS + i] = ldf(pos, i, fl); return; }
    if (i < 24832){ int j=i-24576; cv[CV_EMB + j] = ldf(Wemb, j, fl); return; }
    if (i < 57600){ int j=i-24832; cv[CV_SC  + j] = ldf(Wsc,  j, fl); return; }
    if (i < 57632){ int j=i-57600; cv[CV_PROD+ j] = ldf(wprod,j, fl); return; }
    if (i < 57696){ int j=i-57632; cv[CV_RO0 + j] = ldf(wro0, j, fl); return; }
    if (i < 58720){ int j=i-57696; cv[CV_RO1A+ j] = ldf(Wro1a,j, fl); return; }
    if (i < CVT_WORK){ int j=i-58720; cv[CV_RO1B+ j] = ldf(wro1b,j, fl); return; }
    return;
  }
  // ---- MFMA B-fragment-order bf16 weights, read directly from raw inputs ----
  int i = (b - B_CVT)*256 + tix;       // 20480 exact
  int l = i / SWZ_PER_L, w = i % SWZ_PER_L;
  float v;
  if (w < 2048){
    int t = w >> 9, q = (w >> 7) & 3, n = (w >> 3) & 15, j = w & 7;
    int k = q*8 + j;
    v = (k < 8) ? ldf(Wr1, l*512 + k*64 + t*16 + n, fl) : 0.0f;
  } else if (w < 6144){
    int w2 = w - 2048;
    int nt = w2 >> 10, kt = (w2 >> 9) & 1, q = (w2 >> 7) & 3, n = (w2 >> 3) & 15, j = w2 & 7;
    int k = kt*32 + q*8 + j;
    v = ldf(Wr2, l*4096 + k*64 + nt*16 + n, fl);
  } else {
    int w3 = w - 6144;
    int nt = w3 >> 10, kt = (w3 >> 9) & 1, q = (w3 >> 7) & 3, n = (w3 >> 3) & 15, j = w3 & 7;
    int k = kt*32 + q*8 + j;
    v = ldf(Wr3, l*4096 + k*64 + nt*16 + n, fl);
  }
  swz[i] = f2bs(v);
}

// ============ S2: fused {prefix-scan, h-init, ene-zero} ============
__global__ void k_setup2(const int* __restrict__ deg, int* __restrict__ row_start,
                         int* __restrict__ cursor, const int* __restrict__ types,
                         const float* __restrict__ cvemb, float* __restrict__ h,
                         float* __restrict__ ene){
  if (blockIdx.x == 0){
    __shared__ int lds[1024];
    int t = threadIdx.x;
    if (t < NGRP) ene[t] = 0.0f;
    int v[8]; int tot = 0;
#pragma unroll
    for (int k = 0; k < 8; k++){ v[k] = deg[t*8+k]; tot += v[k]; }
    lds[t] = tot; __syncthreads();
    for (int off = 1; off < 1024; off <<= 1){
      int x = (t >= off) ? lds[t-off] : 0;
      __syncthreads();
      lds[t] += x;
      __syncthreads();
    }
    int base = lds[t] - tot;
#pragma unroll
    for (int k = 0; k < 8; k++){ row_start[t*8+k] = base; cursor[t*8+k] = base; base += v[k]; }
    if (t == 1023) row_start[N_NODES] = base;
  } else {
    int i = (blockIdx.x - 1)*1024 + threadIdx.x;   // 512 blocks x 1024 = N*64
    int n = i >> 6, c = i & 63;
    h[i] = cvemb[types[n]*64 + c];
  }
}

// ============ S3: fused {CSR fill, edge geometry, src-type} ============
__global__ void k_fillgeom(const int* __restrict__ ei, int* __restrict__ cursor,
                           const float* __restrict__ posf, const int* __restrict__ types,
                           int* __restrict__ sslot, unsigned char* __restrict__ tsl,
                           unsigned short* __restrict__ Yb, float* __restrict__ rbuf){
  int e = blockIdx.x*256 + threadIdx.x;
  int s = ei[e], d = ei[N_EDGES + e];
  int slot = atomicAdd(&cursor[d], 1);
  sslot[slot] = s;
  tsl[slot] = (unsigned char)types[s];
  float vx = posf[d*3+0] - posf[s*3+0];
  float vy = posf[d*3+1] - posf[s*3+1];
  float vz = posf[d*3+2] - posf[s*3+2];
  float r = sqrtf(vx*vx + vy*vy + vz*vz + 1e-12f);
  float ir = 1.0f / r;
  float x = vx*ir, y = vy*ir, z = vz*ir;
  const float s3 = 1.7320508075688772f, s15 = 3.872983346207417f, s5 = 2.23606797749979f;
  const float s105 = 10.246950765959598f, s7 = 2.6457513110645907f;
  const float c35 = 2.091650066335189f, c21 = 1.6201851746019651f;
  float x2 = x*x, y2 = y*y, z2 = z*z;
  float ys[16] = {
    1.0f, s3*x, s3*y, s3*z,
    s15*x*y, s15*y*z, 0.5f*s5*(3.0f*z2-1.0f), s15*x*z,
    0.5f*s15*(x2-y2), c35*y*(3.0f*x2-y2), s105*x*y*z, c21*y*(5.0f*z2-1.0f),
    0.5f*s7*(5.0f*z2*z-3.0f*z), c21*x*(5.0f*z2-1.0f), 0.5f*s105*z*(x2-y2),
    c35*x*(x2-3.0f*y2) };
  union { bf16 b[16]; uint4 u[2]; } pk;
#pragma unroll
  for (int k = 0; k < 16; k++) pk.b[k] = __float2bfloat16(ys[k]);
  uint4* yp = (uint4*)(Yb + (size_t)slot*16);
  yp[0] = pk.u[0];
  yp[1] = pk.u[1];
  rbuf[slot] = r;
}

// ====== fused node kernel: {Y(/h) DMA || MFMA radial MLP} -> gather from
//        A_ scratch directly (no RMW phase) -> node update + readout ======
// Block = 4 nodes = contiguous CSR slot range, chunks of 64 slots.
// LAYER_KIND 0: h[src] == Wemb[type[src]] -> 4 preloaded registers, NO gather.
// LAYER_KIND 1: h[src] gathered via global_load_lds; last-block writes output.
#define ROWS 72
template<int LAYER_KIND>
__global__ void __launch_bounds__(256) k_gu(const short* __restrict__ sw,
        const float* __restrict__ rbuf, const unsigned char* __restrict__ tsl,
        const int* __restrict__ sslot,
        const float* __restrict__ h_old, float* __restrict__ h_new,
        const unsigned short* __restrict__ Yb, const int* __restrict__ row_start,
        const int* __restrict__ types, const float* __restrict__ Wsc,
        const float* __restrict__ wprod, const float* __restrict__ wemb,
        const float* __restrict__ wro0,
        const float* __restrict__ Wro1a, const float* __restrict__ wro1b,
        const int* __restrict__ batch, float* __restrict__ ene,
        int* __restrict__ done, const void* __restrict__ pos,
        void* __restrict__ out){
  __shared__ __align__(16) float hS[LAYER_KIND ? 64 : 1][64];   // 16 KB (L1 only)
  __shared__ __align__(16) unsigned short yS[64][16];           //  2 KB
  __shared__ __align__(16) short A_all[4][16*ROWS];             //  9 KB mlp scratch
  __shared__ float ebins[NGRP];
  __shared__ float hn_l[4][64];
  __shared__ int lastBlk;
  int tix = threadIdx.x;
  if (tix < NGRP) ebins[tix] = 0.0f;
  __syncthreads();
  int wv = tix >> 6, lane = tix & 63;
  int q = lane >> 4, nn = lane & 15;
  int n0 = blockIdx.x * 4;
  int n  = n0 + wv;
  int s0 = row_start[n0], sEnd = row_start[n0 + 4];
  int my_beg = row_start[n], my_end = row_start[n + 1];
  short* A = A_all[wv];

  const bf16x8* S1 = (const bf16x8*)(sw);
  const bf16x8* S2 = (const bf16x8*)(sw + 2048);
  const bf16x8* S3 = (const bf16x8*)(sw + 6144);

  // layer-0 embedding rows (4 types x 64 ch) live in 4 registers
  float e0=0.f, e1=0.f, e2=0.f, e3=0.f;
  if (LAYER_KIND == 0){
    e0 = wemb[lane]; e1 = wemb[64+lane]; e2 = wemb[128+lane]; e3 = wemb[192+lane];
  }

  float acc[16];
#pragma unroll
  for (int s = 0; s < 16; s++) acc[s] = 0.0f;

  for (int cb = s0; cb < sEnd; cb += 64){
    int wbase = cb + wv*16;                       // this wave's 16 slots
    int wcnt  = min(16, max(0, sEnd - wbase));
    // ---------- phase A: issue DMAs ----------
    if (LAYER_KIND == 1){
      int sv = sslot[min(wbase + nn, N_EDGES - 1)];
      for (int i = 0; i < wcnt; i++){
        int src = __builtin_amdgcn_readlane(sv, i);
        gl_lds4(h_old + (size_t)src*64 + lane, &hS[wv*16 + i][0]);
      }
    }
    if (wcnt > 0){
      const char* ysrc = (const char*)Yb + (size_t)wbase*32 + lane*4;
      gl_lds4(ysrc,       &yS[wv*16][0]);
      gl_lds4(ysrc + 256, &yS[wv*16 + 8][0]);
    }
    // ---------- phase B: MFMA radial MLP for the 16 slots (hides DMA) ------
    {
      float r = rbuf[min(wbase + nn, N_EDGES - 1)];
      float xc = r * 0.2f;
      float f = 0.0f;
      if (xc < 1.0f){
        float x3 = xc*xc*xc, x6 = x3*x3, x7 = x6*xc, x8 = x7*xc;
        f = 1.0f - 28.0f*x6 + 48.0f*x7 - 21.0f*x8;
      }
      float bs = 0.6324555320336759f * f / r;
      float t0 = PI_F * r * 0.2f;
      bf16x8 af1 = {0,0,0,0,0,0,0,0};
      if (q == 0){
#pragma unroll
        for (int j = 0; j < 8; j++) af1[j] = f2bs(bs * __sinf((float)(j+1) * t0));
      }
      f32x4 macc[4];
#pragma unroll
      for (int t = 0; t < 4; t++){
        bf16x8 b = S1[t*64 + q*16 + nn];
        f32x4 z = {0.f,0.f,0.f,0.f};
        macc[t] = __builtin_amdgcn_mfma_f32_16x16x32_bf16(af1, b, z, 0, 0, 0);
      }
#pragma unroll
      for (int t = 0; t < 4; t++)
#pragma unroll
        for (int rg = 0; rg < 4; rg++)
          A[(q*4+rg)*ROWS + t*16 + nn] = f2bs(silu_f(macc[t][rg]));
      WSYNC();
      bf16x8 a0 = *(const bf16x8*)&A[nn*ROWS + 0*32 + q*8];
      bf16x8 a1 = *(const bf16x8*)&A[nn*ROWS + 1*32 + q*8];
      WSYNC();
#pragma unroll
      for (int t = 0; t < 4; t++){
        f32x4 z = {0.f,0.f,0.f,0.f};
        bf16x8 b0 = S2[t*128 + 0*64 + q*16 + nn];
        bf16x8 b1 = S2[t*128 + 1*64 + q*16 + nn];
        z = __builtin_amdgcn_mfma_f32_16x16x32_bf16(a0, b0, z, 0, 0, 0);
        z = __builtin_amdgcn_mfma_f32_16x16x32_bf16(a1, b1, z, 0, 0, 0);
        macc[t] = z;
      }
#pragma unroll
      for (int t = 0; t < 4; t++)
#pragma unroll
        for (int rg = 0; rg < 4; rg++)
          A[(q*4+rg)*ROWS + t*16 + nn] = f2bs(silu_f(macc[t][rg]));
      WSYNC();
      a0 = *(const bf16x8*)&A[nn*ROWS + 0*32 + q*8];
      a1 = *(const bf16x8*)&A[nn*ROWS + 1*32 + q*8];
      WSYNC();
#pragma unroll
      for (int t = 0; t < 4; t++){
        f32x4 z = {0.f,0.f,0.f,0.f};
        bf16x8 b0 = S3[t*128 + 0*64 + q*16 + nn];
        bf16x8 b1 = S3[t*128 + 1*64 + q*16 + nn];
        z = __builtin_amdgcn_mfma_f32_16x16x32_bf16(a0, b0, z, 0, 0, 0);
        z = __builtin_amdgcn_mfma_f32_16x16x32_bf16(a1, b1, z, 0, 0, 0);
        macc[t] = z;
      }
      // final Rw stays in A (row-major [slot_row][ch], stride ROWS)
#pragma unroll
      for (int t = 0; t < 4; t++)
#pragma unroll
        for (int rg = 0; rg < 4; rg++)
          A[(q*4+rg)*ROWS + t*16 + nn] = f2bs(macc[t][rg]);
    }
    // ---------- wait DMA + make all waves' A visible ----------
    asm volatile("s_waitcnt vmcnt(0)" ::: "memory");
    __syncthreads();
    // ---------- phase D: gather own node's slots; rw read straight from A_ --
    int lo = max(my_beg, cb), hi2 = min(my_end, cb + 64);
    for (int s = lo; s < hi2; s++){
      int L = s - cb;
      float rw = bfbits2f((unsigned short)A_all[L >> 4][(L & 15)*ROWS + lane]);
      float hv;
      if (LAYER_KIND == 0){
        int ty = __builtin_amdgcn_readfirstlane((int)tsl[s]);
        hv = (ty & 2) ? ((ty & 1) ? e3 : e2) : ((ty & 1) ? e1 : e0);
      } else {
        hv = hS[L][lane];
      }
      float g = rw * hv;
      const uint4* yq = (const uint4*)&yS[L][0];   // uniform -> broadcast
      uint4 ya = yq[0], yb_ = yq[1];
      float lo2, hi3;
      unpack2(ya.x, lo2, hi3); acc[0]  += g*lo2; acc[1]  += g*hi3;
      unpack2(ya.y, lo2, hi3); acc[2]  += g*lo2; acc[3]  += g*hi3;
      unpack2(ya.z, lo2, hi3); acc[4]  += g*lo2; acc[5]  += g*hi3;
      unpack2(ya.w, lo2, hi3); acc[6]  += g*lo2; acc[7]  += g*hi3;
      unpack2(yb_.x, lo2, hi3); acc[8]  += g*lo2; acc[9]  += g*hi3;
      unpack2(yb_.y, lo2, hi3); acc[10] += g*lo2; acc[11] += g*hi3;
      unpack2(yb_.z, lo2, hi3); acc[12] += g*lo2; acc[13] += g*hi3;
      unpack2(yb_.w, lo2, hi3); acc[14] += g*lo2; acc[15] += g*hi3;
    }
    __syncthreads();   // protect yS/hS/A_ before next chunk's DMA/MLP
  }
#pragma unroll
  for (int s = 0; s < 16; s++) acc[s] *= INV_AVG;

  int ty = __builtin_amdgcn_readfirstlane(types[n]);
  const float* Ws = Wsc + (size_t)ty*4096;
  float sc0 = 0.f, sc1 = 0.f, sc2 = 0.f, sc3 = 0.f;
#pragma unroll
  for (int c = 0; c < 64; c += 4){
    sc0 += h_old[(size_t)n*64 + c+0] * Ws[(c+0)*64 + lane];
    sc1 += h_old[(size_t)n*64 + c+1] * Ws[(c+1)*64 + lane];
    sc2 += h_old[(size_t)n*64 + c+2] * Ws[(c+2)*64 + lane];
    sc3 += h_old[(size_t)n*64 + c+3] * Ws[(c+3)*64 + lane];
  }
  float sc = (sc0 + sc1) + (sc2 + sc3);

  float inv0 = acc[0];
  float inv1 = acc[1]*acc[1] + acc[2]*acc[2] + acc[3]*acc[3];
  float inv2 = acc[4]*acc[4] + acc[5]*acc[5] + acc[6]*acc[6] + acc[7]*acc[7]
             + acc[8]*acc[8];
  float inv3 = acc[9]*acc[9] + acc[10]*acc[10] + acc[11]*acc[11] + acc[12]*acc[12]
             + acc[13]*acc[13] + acc[14]*acc[14] + acc[15]*acc[15];
  const float* wp = wprod + ty*4;
  float hn = inv0*wp[0] + inv1*wp[1] + inv2*wp[2] + inv3*wp[3] + sc;
  h_new[(size_t)n*64 + lane] = hn;

  float ev;
  if (LAYER_KIND == 0){
    float p = hn * wro0[lane];
#pragma unroll
    for (int off = 32; off >= 1; off >>= 1) p += __shfl_xor(p, off, 64);
    ev = p;
  } else {
    hn_l[wv][lane] = hn;
    int j = lane & 15;
    float pj = 0.0f;
#pragma unroll
    for (int c = 0; c < 64; c++)
      pj += hn_l[wv][c] * Wro1a[c*16 + j];
    float evj = silu_f(pj) * wro1b[j];
    evj += __shfl_xor(evj, 8, 64);
    evj += __shfl_xor(evj, 4, 64);
    evj += __shfl_xor(evj, 2, 64);
    evj += __shfl_xor(evj, 1, 64);
    ev = evj;
  }
  if (lane == 0) atomicAdd(&ebins[batch[n]], ev);
  __syncthreads();
  if (tix < NGRP){
    float v = ebins[tix];
    if (v != 0.0f) atomicAdd(&ene[tix], v);
    __threadfence();
  }
  if (LAYER_KIND == 1){
    // last-block-to-finish writes the output (folds the k_out dispatch)
    __syncthreads();
    if (tix == 0) lastBlk = (atomicAdd(done, 1) == (int)gridDim.x - 1) ? 1 : 0;
    __syncthreads();
    if (lastBlk){
      int fl = detect_fl(pos);
      if (tix < NGRP){
        float v = atomicAdd(&ene[tix], 0.0f);   // device-scope coherent read
        if (fl) ((bf16*)out)[tix] = __float2bfloat16(v);
        else    ((float*)out)[tix] = v;
      }
    }
  }
}

static inline size_t rup(size_t x){ return (x + 255) & ~(size_t)255; }

extern "C" void kernel_launch(void* const* d_in, const int* in_sizes, int n_in,
                              void* d_out, int out_size, void* d_ws, size_t ws_size,
                              hipStream_t stream) {
  const void* pos   = d_in[0];
  const int*  types = (const int*)d_in[1];
  const int*  ei    = (const int*)d_in[2];
  const int*  batch = (const int*)d_in[3];
  const void* Wemb  = d_in[4];
  const void* Wr1   = d_in[5];
  const void* Wr2   = d_in[6];
  const void* Wr3   = d_in[7];
  const void* Wsc   = d_in[8];
  const void* wprod = d_in[9];
  const void* wro0  = d_in[10];
  const void* Wro1a = d_in[11];
  const void* wro1b = d_in[12];

  char* w = (char*)d_ws;
  float* cv       = (float*)w; w += rup((size_t)CVT_N*4);
  short* swz      = (short*)w; w += rup((size_t)SWZ_N*2);
  float* ene      = (float*)w; w += 256;
  int*   deg      = (int*)  w; w += rup((size_t)N_NODES*4 + 256);  // +done
  int*   row_start= (int*)  w; w += rup((size_t)(N_NODES+1)*4);
  int*   cursor   = (int*)  w; w += rup((size_t)N_NODES*4);
  int*   sslot    = (int*)  w; w += rup((size_t)N_EDGES*4);
  unsigned char* tsl = (unsigned char*)w; w += rup((size_t)N_EDGES);
  float* h0       = (float*)w; w += rup((size_t)N_NODES*64*4);
  float* h1       = (float*)w; w += rup((size_t)N_NODES*64*4);
  float* rbuf     = (float*)w; w += rup((size_t)N_EDGES*4);
  unsigned short* Yb = (unsigned short*)w; w += rup((size_t)N_EDGES*16*2);
  w += 4096;   // DMA over-read slack past Yb (tail Y reads <=768B past end)
  int* done = deg + N_NODES;

  hipMemsetAsync(deg, 0, N_NODES*4 + 256, stream);   // deg + done

  const int* dstp = ei + N_EDGES;
  k_setup1<<<B_CVT + B_SWZ + B_HIST, 256, 0, stream>>>(
      pos, Wemb, Wsc, wprod, wro0, Wro1a, wro1b, Wr1, Wr2, Wr3, dstp, cv, swz, deg);
  k_setup2<<<1 + (N_NODES*64)/1024, 1024, 0, stream>>>(
      deg, row_start, cursor, types, cv + CV_EMB, h0, ene);
  k_fillgeom<<<N_EDGES/256, 256, 0, stream>>>(ei, cursor, cv + CV_POS, types,
      sslot, tsl, Yb, rbuf);

  k_gu<0><<<N_NODES/4, 256, 0, stream>>>(swz, rbuf, tsl, sslot, h0, h1, Yb,
      row_start, types, cv + CV_SC, cv + CV_PROD, cv + CV_EMB,
      cv + CV_RO0, cv + CV_RO1A, cv + CV_RO1B, batch, ene, done, pos, d_out);
  k_gu<1><<<N_NODES/4, 256, 0, stream>>>(swz + SWZ_PER_L, rbuf, tsl, sslot, h1, h0, Yb,
      row_start, types, cv + CV_SC + (size_t)NELM*4096, cv + CV_PROD + NELM*4,
      cv + CV_EMB, cv + CV_RO0, cv + CV_RO1A, cv + CV_RO1B, batch, ene, done,
      pos, d_out);
}

// Round 6
// 242.929 us; speedup vs baseline: 1.0906x; 1.0906x over previous
//
#include <hip/hip_runtime.h>
#include <hip/hip_bf16.h>
#include <math.h>

#define N_NODES 8192
#define N_EDGES 131072
#define NGRP 16
#define NLAY 2
#define NELM 4
constexpr float INV_AVG = 1.0f / 16.0f;
constexpr float PI_F = 3.14159265358979323846f;

// converted fp32 buffer layout (element offsets).
#define CV_POS   0        // 24576
#define CV_EMB   24576    // 256
#define CV_SC    42240    // 32768 (natural [l][ty][c:64][d:64])
#define CV_PROD  75008    // 32
#define CV_RO0   75040    // 64
#define CV_RO1A  75104    // 1024
#define CV_RO1B  76128    // 16
#define CVT_N    76144

// swizzled bf16 MFMA B-fragment weight buffer: per layer 10240 shorts
#define SWZ_PER_L 10240
#define SWZ_N     20480

// setup1 fused-dispatch block ranges
#define B_CVT  230
#define B_SWZ  80
#define B_HIST 512
#define CVT_WORK 58736

typedef __hip_bfloat16 bf16;
typedef __attribute__((ext_vector_type(8))) short bf16x8;
typedef __attribute__((ext_vector_type(4))) float f32x4;

__device__ __forceinline__ float silu_f(float x){ return x / (1.0f + __expf(-x)); }
__device__ __forceinline__ float bfbits2f(unsigned short u){
  return __uint_as_float(((unsigned)u) << 16);
}
__device__ __forceinline__ void unpack2(unsigned u, float& lo, float& hi){
  lo = __uint_as_float(u << 16);
  hi = __uint_as_float(u & 0xffff0000u);
}
__device__ __forceinline__ short f2bs(float v){
  union { bf16 b; short s; } u; u.b = __float2bfloat16(v); return u.s;
}
__device__ __forceinline__ float ldf(const void* p, int i, int flag){
  if (flag) return bfbits2f(((const unsigned short*)p)[i]);
  return ((const float*)p)[i];
}
// per-wave input dtype detection (reads first 128 ushorts of pos; L1/L2-hot).
__device__ __forceinline__ int detect_fl(const void* pos){
  int lane = threadIdx.x & 63;
  const unsigned short* u = (const unsigned short*)pos;
  float va = bfbits2f(u[2*lane]), vb = bfbits2f(u[2*lane+1]);
  bool bad = !(fabsf(va) <= 1000.0f) || !(fabsf(vb) <= 1000.0f);
  return (__ballot(bad) == 0ull) ? 1 : 0;
}
__device__ __forceinline__ void WSYNC(){ __builtin_amdgcn_wave_barrier(); }

// async global->LDS DMA: data never touches VGPRs. LDS dest wave-uniform,
// +lane*size implicit; global src per-lane.
__device__ __forceinline__ void gl_lds4(const void* g, void* l){
  __builtin_amdgcn_global_load_lds(
      (const __attribute__((address_space(1))) unsigned*)g,
      (__attribute__((address_space(3))) unsigned*)l, 4, 0, 0);
}
__device__ __forceinline__ void gl_lds16(const void* g, void* l){
  __builtin_amdgcn_global_load_lds(
      (const __attribute__((address_space(1))) unsigned*)g,
      (__attribute__((address_space(3))) unsigned*)l, 16, 0, 0);
}

// ============ S1: fused {detect, cvt, weight-swizzle, degree-hist} ============
__global__ void k_setup1(const void* __restrict__ pos, const void* __restrict__ Wemb,
                         const void* __restrict__ Wsc, const void* __restrict__ wprod,
                         const void* __restrict__ wro0, const void* __restrict__ Wro1a,
                         const void* __restrict__ wro1b, const void* __restrict__ Wr1,
                         const void* __restrict__ Wr2, const void* __restrict__ Wr3,
                         const int* __restrict__ dstp, float* __restrict__ cv,
                         short* __restrict__ swz, int* __restrict__ deg){
  int b = blockIdx.x, tix = threadIdx.x;
  if (b >= B_CVT + B_SWZ){            // ---- degree histogram ----
    int e = (b - B_CVT - B_SWZ)*256 + tix;
    atomicAdd(&deg[dstp[e]], 1);
    return;
  }
  int fl = detect_fl(pos);
  if (b < B_CVT){                      // ---- fp32 conversion ----
    int i = b*256 + tix;
    if (i < 24576){ cv[CV_POS + i] = ldf(pos, i, fl); return; }
    if (i < 24832){ int j=i-24576; cv[CV_EMB + j] = ldf(Wemb, j, fl); return; }
    if (i < 57600){ int j=i-24832; cv[CV_SC  + j] = ldf(Wsc,  j, fl); return; }
    if (i < 57632){ int j=i-57600; cv[CV_PROD+ j] = ldf(wprod,j, fl); return; }
    if (i < 57696){ int j=i-57632; cv[CV_RO0 + j] = ldf(wro0, j, fl); return; }
    if (i < 58720){ int j=i-57696; cv[CV_RO1A+ j] = ldf(Wro1a,j, fl); return; }
    if (i < CVT_WORK){ int j=i-58720; cv[CV_RO1B+ j] = ldf(wro1b,j, fl); return; }
    return;
  }
  // ---- MFMA B-fragment-order bf16 weights, read directly from raw inputs ----
  int i = (b - B_CVT)*256 + tix;       // 20480 exact
  int l = i / SWZ_PER_L, w = i % SWZ_PER_L;
  float v;
  if (w < 2048){
    int t = w >> 9, q = (w >> 7) & 3, n = (w >> 3) & 15, j = w & 7;
    int k = q*8 + j;
    v = (k < 8) ? ldf(Wr1, l*512 + k*64 + t*16 + n, fl) : 0.0f;
  } else if (w < 6144){
    int w2 = w - 2048;
    int nt = w2 >> 10, kt = (w2 >> 9) & 1, q = (w2 >> 7) & 3, n = (w2 >> 3) & 15, j = w2 & 7;
    int k = kt*32 + q*8 + j;
    v = ldf(Wr2, l*4096 + k*64 + nt*16 + n, fl);
  } else {
    int w3 = w - 6144;
    int nt = w3 >> 10, kt = (w3 >> 9) & 1, q = (w3 >> 7) & 3, n = (w3 >> 3) & 15, j = w3 & 7;
    int k = kt*32 + q*8 + j;
    v = ldf(Wr3, l*4096 + k*64 + nt*16 + n, fl);
  }
  swz[i] = f2bs(v);
}

// ============ S2: fused {prefix-scan, h-init, ene-zero} ============
__global__ void k_setup2(const int* __restrict__ deg, int* __restrict__ row_start,
                         int* __restrict__ cursor, const int* __restrict__ types,
                         const float* __restrict__ cvemb, float* __restrict__ h,
                         float* __restrict__ ene){
  if (blockIdx.x == 0){
    __shared__ int lds[1024];
    int t = threadIdx.x;
    if (t < NGRP) ene[t] = 0.0f;
    int v[8]; int tot = 0;
#pragma unroll
    for (int k = 0; k < 8; k++){ v[k] = deg[t*8+k]; tot += v[k]; }
    lds[t] = tot; __syncthreads();
    for (int off = 1; off < 1024; off <<= 1){
      int x = (t >= off) ? lds[t-off] : 0;
      __syncthreads();
      lds[t] += x;
      __syncthreads();
    }
    int base = lds[t] - tot;
#pragma unroll
    for (int k = 0; k < 8; k++){ row_start[t*8+k] = base; cursor[t*8+k] = base; base += v[k]; }
    if (t == 1023) row_start[N_NODES] = base;
  } else {
    int i = (blockIdx.x - 1)*1024 + threadIdx.x;   // 512 blocks x 1024 = N*64
    int n = i >> 6, c = i & 63;
    h[i] = cvemb[types[n]*64 + c];
  }
}

// ============ S3: fused {CSR fill, edge geometry, src-type} ============
__global__ void k_fillgeom(const int* __restrict__ ei, int* __restrict__ cursor,
                           const float* __restrict__ posf, const int* __restrict__ types,
                           int* __restrict__ sslot, unsigned char* __restrict__ tsl,
                           unsigned short* __restrict__ Yb, float* __restrict__ rbuf){
  int e = blockIdx.x*256 + threadIdx.x;
  int s = ei[e], d = ei[N_EDGES + e];
  int slot = atomicAdd(&cursor[d], 1);
  sslot[slot] = s;
  tsl[slot] = (unsigned char)types[s];
  float vx = posf[d*3+0] - posf[s*3+0];
  float vy = posf[d*3+1] - posf[s*3+1];
  float vz = posf[d*3+2] - posf[s*3+2];
  float r = sqrtf(vx*vx + vy*vy + vz*vz + 1e-12f);
  float ir = 1.0f / r;
  float x = vx*ir, y = vy*ir, z = vz*ir;
  const float s3 = 1.7320508075688772f, s15 = 3.872983346207417f, s5 = 2.23606797749979f;
  const float s105 = 10.246950765959598f, s7 = 2.6457513110645907f;
  const float c35 = 2.091650066335189f, c21 = 1.6201851746019651f;
  float x2 = x*x, y2 = y*y, z2 = z*z;
  float ys[16] = {
    1.0f, s3*x, s3*y, s3*z,
    s15*x*y, s15*y*z, 0.5f*s5*(3.0f*z2-1.0f), s15*x*z,
    0.5f*s15*(x2-y2), c35*y*(3.0f*x2-y2), s105*x*y*z, c21*y*(5.0f*z2-1.0f),
    0.5f*s7*(5.0f*z2*z-3.0f*z), c21*x*(5.0f*z2-1.0f), 0.5f*s105*z*(x2-y2),
    c35*x*(x2-3.0f*y2) };
  union { bf16 b[16]; uint4 u[2]; } pk;
#pragma unroll
  for (int k = 0; k < 16; k++) pk.b[k] = __float2bfloat16(ys[k]);
  uint4* yp = (uint4*)(Yb + (size_t)slot*16);
  yp[0] = pk.u[0];
  yp[1] = pk.u[1];
  rbuf[slot] = r;
}

// ===== MFMA radial MLP (8->64->64->64) for BOTH layers -> Rw[l][slot][c] =====
#define ROWS 72
__global__ void __launch_bounds__(256) k_mlp2(const float* __restrict__ rbuf,
        const short* __restrict__ sw, bf16* __restrict__ Rwb){
  __shared__ short lds[4][16*ROWS];   // wave-private slices
  int tix = threadIdx.x;
  int wv = tix >> 6, lane = tix & 63;
  int q = lane >> 4, nn = lane & 15;
  int ebase = blockIdx.x*64 + wv*16;

  float r = rbuf[ebase + nn];
  float xc = r * 0.2f;
  float f = 0.0f;
  if (xc < 1.0f){
    float x3 = xc*xc*xc, x6 = x3*x3, x7 = x6*xc, x8 = x7*xc;
    f = 1.0f - 28.0f*x6 + 48.0f*x7 - 21.0f*x8;
  }
  float bs = 0.6324555320336759f * f / r;
  float t0 = PI_F * r * 0.2f;
  float ef[8];
#pragma unroll
  for (int k = 0; k < 8; k++) ef[k] = bs * __sinf((float)(k+1) * t0);

  bf16x8 af1 = {0,0,0,0,0,0,0,0};
  if (q == 0){
#pragma unroll
    for (int j = 0; j < 8; j++) af1[j] = f2bs(ef[j]);
  }
  short* A = lds[wv];
  int row = lane >> 2, c4 = lane & 3;

  for (int l = 0; l < NLAY; l++){
    const bf16x8* S1 = (const bf16x8*)(sw + l*SWZ_PER_L);
    const bf16x8* S2 = (const bf16x8*)(sw + l*SWZ_PER_L + 2048);
    const bf16x8* S3 = (const bf16x8*)(sw + l*SWZ_PER_L + 6144);
    f32x4 acc[4];
#pragma unroll
    for (int t = 0; t < 4; t++){
      bf16x8 b = S1[t*64 + q*16 + nn];
      f32x4 z = {0.f,0.f,0.f,0.f};
      acc[t] = __builtin_amdgcn_mfma_f32_16x16x32_bf16(af1, b, z, 0, 0, 0);
    }
#pragma unroll
    for (int t = 0; t < 4; t++)
#pragma unroll
      for (int rg = 0; rg < 4; rg++)
        A[(q*4+rg)*ROWS + t*16 + nn] = f2bs(silu_f(acc[t][rg]));
    WSYNC();

    bf16x8 a0 = *(const bf16x8*)&A[nn*ROWS + 0*32 + q*8];
    bf16x8 a1 = *(const bf16x8*)&A[nn*ROWS + 1*32 + q*8];
    WSYNC();
#pragma unroll
    for (int t = 0; t < 4; t++){
      f32x4 z = {0.f,0.f,0.f,0.f};
      bf16x8 b0 = S2[t*128 + 0*64 + q*16 + nn];
      bf16x8 b1 = S2[t*128 + 1*64 + q*16 + nn];
      z = __builtin_amdgcn_mfma_f32_16x16x32_bf16(a0, b0, z, 0, 0, 0);
      z = __builtin_amdgcn_mfma_f32_16x16x32_bf16(a1, b1, z, 0, 0, 0);
      acc[t] = z;
    }
#pragma unroll
    for (int t = 0; t < 4; t++)
#pragma unroll
      for (int rg = 0; rg < 4; rg++)
        A[(q*4+rg)*ROWS + t*16 + nn] = f2bs(silu_f(acc[t][rg]));
    WSYNC();

    a0 = *(const bf16x8*)&A[nn*ROWS + 0*32 + q*8];
    a1 = *(const bf16x8*)&A[nn*ROWS + 1*32 + q*8];
    WSYNC();
#pragma unroll
    for (int t = 0; t < 4; t++){
      f32x4 z = {0.f,0.f,0.f,0.f};
      bf16x8 b0 = S3[t*128 + 0*64 + q*16 + nn];
      bf16x8 b1 = S3[t*128 + 1*64 + q*16 + nn];
      z = __builtin_amdgcn_mfma_f32_16x16x32_bf16(a0, b0, z, 0, 0, 0);
      z = __builtin_amdgcn_mfma_f32_16x16x32_bf16(a1, b1, z, 0, 0, 0);
      acc[t] = z;
    }
#pragma unroll
    for (int t = 0; t < 4; t++)
#pragma unroll
      for (int rg = 0; rg < 4; rg++)
        A[(q*4+rg)*ROWS + t*16 + nn] = f2bs(acc[t][rg]);
    WSYNC();

    uint4 u0 = *(const uint4*)&A[row*ROWS + c4*16];
    uint4 u1 = *(const uint4*)&A[row*ROWS + c4*16 + 8];
    uint4* gp = (uint4*)((unsigned short*)Rwb + (size_t)l*N_EDGES*64
                         + ((size_t)(ebase + row))*64 + c4*16);
    gp[0] = u0;
    gp[1] = u1;
    WSYNC();   // before next layer overwrites A
  }
}

// ------- node update + readout: fully wave-independent, async LDS DMA ------
// Wave owns node n; 16-slot chunks. LAYER_KIND 0: h[src]=Wemb[type[src]] from
// 4 registers + per-chunk type vector (NO gather, small LDS). LAYER_KIND 1:
// h gathered via global_load_lds (R3-verified design); last block writes out.
template<int LAYER_KIND>
__global__ void __launch_bounds__(256) k_gu(const bf16* __restrict__ Rwb,
        const float* __restrict__ h_old, float* __restrict__ h_new,
        const unsigned short* __restrict__ Yb, const int* __restrict__ row_start,
        const int* __restrict__ sslot, const unsigned char* __restrict__ tsl,
        const int* __restrict__ types, const float* __restrict__ Wsc,
        const float* __restrict__ wprod, const float* __restrict__ wemb,
        const float* __restrict__ wro0,
        const float* __restrict__ Wro1a, const float* __restrict__ wro1b,
        const int* __restrict__ batch, float* __restrict__ ene,
        int* __restrict__ done, const void* __restrict__ pos,
        void* __restrict__ out){
  __shared__ __align__(16) float          hS[LAYER_KIND ? 4 : 1][16][64];
  __shared__ __align__(16) unsigned short rwS[4][16][64];  // 8 KB
  __shared__ __align__(16) unsigned short yS[4][16][16];   // 2 KB
  __shared__ float ebins[NGRP];
  __shared__ float hn_l[4][64];
  __shared__ int lastBlk;
  int tix = threadIdx.x;
  if (tix < NGRP) ebins[tix] = 0.0f;
  __syncthreads();
  int wv = tix >> 6, lane = tix & 63;
  int n = blockIdx.x * 4 + wv;
  int beg = row_start[n], end = row_start[n + 1];
  const unsigned short* RW = (const unsigned short*)Rwb;

  // layer-0 embedding rows (4 types x 64 ch) in registers
  float e0=0.f, e1=0.f, e2=0.f, e3=0.f;
  if (LAYER_KIND == 0){
    e0 = wemb[lane]; e1 = wemb[64+lane]; e2 = wemb[128+lane]; e3 = wemb[192+lane];
  }

  float acc[16];
#pragma unroll
  for (int s = 0; s < 16; s++) acc[s] = 0.0f;

  for (int cb = beg; cb < end; cb += 16){
    int cnt = min(16, end - cb);
    WSYNC();   // fence: prior chunk's LDS reads precede this chunk's DMA
    // ---- independent DMAs first: Rw rows (2x1KB) + Y rows (2x256B) ----
    const char* rwsrc = (const char*)RW + (size_t)cb*128 + lane*16;
    gl_lds16(rwsrc,        &rwS[wv][0][0]);
    gl_lds16(rwsrc + 1024, &rwS[wv][8][0]);
    const char* ysrc = (const char*)Yb + (size_t)cb*32 + lane*4;
    gl_lds4(ysrc,       &yS[wv][0][0]);
    gl_lds4(ysrc + 256, &yS[wv][8][0]);
    int tv = 0;
    if (LAYER_KIND == 0){
      // chunk slot-types into a register (ONE vector load; no per-slot loads)
      tv = (int)tsl[min(cb + (lane & 15), N_EDGES - 1)];
    } else {
      int sv = sslot[min(cb + (lane & 15), N_EDGES - 1)];
      for (int i = 0; i < cnt; i++){
        int src = __builtin_amdgcn_readlane(sv, i);
        gl_lds4(h_old + (size_t)src*64 + lane, &hS[wv][i][0]);
      }
    }
    asm volatile("s_waitcnt vmcnt(0)" ::: "memory");
    __builtin_amdgcn_sched_barrier(0);
    // ---- compute from LDS (wave-private buffers; no block barrier) ----
    for (int i = 0; i < cnt; i++){
      float rw = bfbits2f(rwS[wv][i][lane]);
      float hv;
      if (LAYER_KIND == 0){
        int ty = __builtin_amdgcn_readlane(tv, i);
        hv = (ty & 2) ? ((ty & 1) ? e3 : e2) : ((ty & 1) ? e1 : e0);
      } else {
        hv = hS[wv][i][lane];
      }
      float g = rw * hv;
      const uint4* yq = (const uint4*)&yS[wv][i][0];   // uniform -> broadcast
      uint4 ya = yq[0], yb = yq[1];
      float lo, hi;
      unpack2(ya.x, lo, hi); acc[0]  += g*lo; acc[1]  += g*hi;
      unpack2(ya.y, lo, hi); acc[2]  += g*lo; acc[3]  += g*hi;
      unpack2(ya.z, lo, hi); acc[4]  += g*lo; acc[5]  += g*hi;
      unpack2(ya.w, lo, hi); acc[6]  += g*lo; acc[7]  += g*hi;
      unpack2(yb.x, lo, hi); acc[8]  += g*lo; acc[9]  += g*hi;
      unpack2(yb.y, lo, hi); acc[10] += g*lo; acc[11] += g*hi;
      unpack2(yb.z, lo, hi); acc[12] += g*lo; acc[13] += g*hi;
      unpack2(yb.w, lo, hi); acc[14] += g*lo; acc[15] += g*hi;
    }
  }
#pragma unroll
  for (int s = 0; s < 16; s++) acc[s] *= INV_AVG;

  int ty = __builtin_amdgcn_readfirstlane(types[n]);
  const float* Ws = Wsc + (size_t)ty*4096;
  float sc0 = 0.f, sc1 = 0.f, sc2 = 0.f, sc3 = 0.f;
#pragma unroll
  for (int c = 0; c < 64; c += 4){
    sc0 += h_old[(size_t)n*64 + c+0] * Ws[(c+0)*64 + lane];
    sc1 += h_old[(size_t)n*64 + c+1] * Ws[(c+1)*64 + lane];
    sc2 += h_old[(size_t)n*64 + c+2] * Ws[(c+2)*64 + lane];
    sc3 += h_old[(size_t)n*64 + c+3] * Ws[(c+3)*64 + lane];
  }
  float sc = (sc0 + sc1) + (sc2 + sc3);

  float inv0 = acc[0];
  float inv1 = acc[1]*acc[1] + acc[2]*acc[2] + acc[3]*acc[3];
  float inv2 = acc[4]*acc[4] + acc[5]*acc[5] + acc[6]*acc[6] + acc[7]*acc[7]
             + acc[8]*acc[8];
  float inv3 = acc[9]*acc[9] + acc[10]*acc[10] + acc[11]*acc[11] + acc[12]*acc[12]
             + acc[13]*acc[13] + acc[14]*acc[14] + acc[15]*acc[15];
  const float* wp = wprod + ty*4;
  float hn = inv0*wp[0] + inv1*wp[1] + inv2*wp[2] + inv3*wp[3] + sc;
  h_new[(size_t)n*64 + lane] = hn;

  float ev;
  if (LAYER_KIND == 0){
    float p = hn * wro0[lane];
#pragma unroll
    for (int off = 32; off >= 1; off >>= 1) p += __shfl_xor(p, off, 64);
    ev = p;
  } else {
    hn_l[wv][lane] = hn;
    int j = lane & 15;
    float pj = 0.0f;
#pragma unroll
    for (int c = 0; c < 64; c++)
      pj += hn_l[wv][c] * Wro1a[c*16 + j];
    float evj = silu_f(pj) * wro1b[j];
    evj += __shfl_xor(evj, 8, 64);
    evj += __shfl_xor(evj, 4, 64);
    evj += __shfl_xor(evj, 2, 64);
    evj += __shfl_xor(evj, 1, 64);
    ev = evj;
  }
  if (lane == 0) atomicAdd(&ebins[batch[n]], ev);
  __syncthreads();
  if (tix < NGRP){
    float v = ebins[tix];
    if (v != 0.0f) atomicAdd(&ene[tix], v);
  }
  if (LAYER_KIND == 1){
    // fold final output write: last block to pass the ticket does it.
    // __syncthreads drains each wave's outstanding atomics (vmcnt) -> no fence.
    __syncthreads();
    if (tix == 0) lastBlk = (atomicAdd(done, 1) == (int)gridDim.x - 1) ? 1 : 0;
    __syncthreads();
    if (lastBlk){
      int fl = detect_fl(pos);
      if (tix < NGRP){
        float v = atomicAdd(&ene[tix], 0.0f);   // coherent device-scope read
        if (fl) ((bf16*)out)[tix] = __float2bfloat16(v);
        else    ((float*)out)[tix] = v;
      }
    }
  }
}

static inline size_t rup(size_t x){ return (x + 255) & ~(size_t)255; }

extern "C" void kernel_launch(void* const* d_in, const int* in_sizes, int n_in,
                              void* d_out, int out_size, void* d_ws, size_t ws_size,
                              hipStream_t stream) {
  const void* pos   = d_in[0];
  const int*  types = (const int*)d_in[1];
  const int*  ei    = (const int*)d_in[2];
  const int*  batch = (const int*)d_in[3];
  const void* Wemb  = d_in[4];
  const void* Wr1   = d_in[5];
  const void* Wr2   = d_in[6];
  const void* Wr3   = d_in[7];
  const void* Wsc   = d_in[8];
  const void* wprod = d_in[9];
  const void* wro0  = d_in[10];
  const void* Wro1a = d_in[11];
  const void* wro1b = d_in[12];

  char* w = (char*)d_ws;
  float* cv       = (float*)w; w += rup((size_t)CVT_N*4);
  short* swz      = (short*)w; w += rup((size_t)SWZ_N*2);
  float* ene      = (float*)w; w += 256;
  int*   deg      = (int*)  w; w += rup((size_t)N_NODES*4 + 256);  // +done
  int*   row_start= (int*)  w; w += rup((size_t)(N_NODES+1)*4);
  int*   cursor   = (int*)  w; w += rup((size_t)N_NODES*4);
  int*   sslot    = (int*)  w; w += rup((size_t)N_EDGES*4);
  unsigned char* tsl = (unsigned char*)w; w += rup((size_t)N_EDGES);
  float* h0       = (float*)w; w += rup((size_t)N_NODES*64*4);
  float* h1       = (float*)w; w += rup((size_t)N_NODES*64*4);
  float* rbuf     = (float*)w; w += rup((size_t)N_EDGES*4);
  unsigned short* Yb = (unsigned short*)w; w += rup((size_t)N_EDGES*16*2);
  bf16*  Rwb      = (bf16*) w; w += rup((size_t)NLAY*N_EDGES*64*2);
  w += 4096;   // DMA over-read slack (tail chunks read <=2KB past Rwb/Yb ends)
  int* done = deg + N_NODES;

  hipMemsetAsync(deg, 0, N_NODES*4 + 256, stream);   // deg + done ticket

  const int* dstp = ei + N_EDGES;
  k_setup1<<<B_CVT + B_SWZ + B_HIST, 256, 0, stream>>>(
      pos, Wemb, Wsc, wprod, wro0, Wro1a, wro1b, Wr1, Wr2, Wr3, dstp, cv, swz, deg);
  k_setup2<<<1 + (N_NODES*64)/1024, 1024, 0, stream>>>(
      deg, row_start, cursor, types, cv + CV_EMB, h0, ene);
  k_fillgeom<<<N_EDGES/256, 256, 0, stream>>>(ei, cursor, cv + CV_POS, types,
      sslot, tsl, Yb, rbuf);
  k_mlp2<<<N_EDGES/64, 256, 0, stream>>>(rbuf, swz, Rwb);

  k_gu<0><<<N_NODES/4, 256, 0, stream>>>(Rwb, h0, h1, Yb,
      row_start, sslot, tsl, types, cv + CV_SC, cv + CV_PROD, cv + CV_EMB,
      cv + CV_RO0, cv + CV_RO1A, cv + CV_RO1B, batch, ene, done, pos, d_out);
  k_gu<1><<<N_NODES/4, 256, 0, stream>>>(Rwb + (size_t)N_EDGES*64, h1, h0, Yb,
      row_start, sslot, tsl, types, cv + CV_SC + (size_t)NELM*4096,
      cv + CV_PROD + NELM*4, cv + CV_EMB,
      cv + CV_RO0, cv + CV_RO1A, cv + CV_RO1B, batch, ene, done, pos, d_out);
}

// Round 7
// 200.682 us; speedup vs baseline: 1.3202x; 1.2105x over previous
//
#include <hip/hip_runtime.h>
#include <hip/hip_bf16.h>
#include <math.h>

#define N_NODES 8192
#define N_EDGES 131072
#define NGRP 16
#define NLAY 2
#define NELM 4
constexpr float INV_AVG = 1.0f / 16.0f;
constexpr float PI_F = 3.14159265358979323846f;

// converted fp32 buffer layout (element offsets).
#define CV_POS   0        // 24576
#define CV_EMB   24576    // 256
#define CV_SC    42240    // 32768 (natural [l][ty][c:64][d:64])
#define CV_PROD  75008    // 32
#define CV_RO0   75040    // 64
#define CV_RO1A  75104    // 1024
#define CV_RO1B  76128    // 16
#define CVT_N    76144

// swizzled bf16 MFMA B-fragment weight buffer: per layer 10240 shorts
#define SWZ_PER_L 10240
#define SWZ_N     20480

// setup1 fused-dispatch block ranges
#define B_CVT  230
#define B_SWZ  80
#define B_HIST 512
#define CVT_WORK 58736

typedef __hip_bfloat16 bf16;
typedef __attribute__((ext_vector_type(8))) short bf16x8;
typedef __attribute__((ext_vector_type(4))) float f32x4;

__device__ __forceinline__ float silu_f(float x){ return x / (1.0f + __expf(-x)); }
__device__ __forceinline__ float bfbits2f(unsigned short u){
  return __uint_as_float(((unsigned)u) << 16);
}
__device__ __forceinline__ void unpack2(unsigned u, float& lo, float& hi){
  lo = __uint_as_float(u << 16);
  hi = __uint_as_float(u & 0xffff0000u);
}
__device__ __forceinline__ short f2bs(float v){
  union { bf16 b; short s; } u; u.b = __float2bfloat16(v); return u.s;
}
__device__ __forceinline__ float ldf(const void* p, int i, int flag){
  if (flag) return bfbits2f(((const unsigned short*)p)[i]);
  return ((const float*)p)[i];
}
// per-wave input dtype detection (reads first 128 ushorts of pos; L1/L2-hot).
__device__ __forceinline__ int detect_fl(const void* pos){
  int lane = threadIdx.x & 63;
  const unsigned short* u = (const unsigned short*)pos;
  float va = bfbits2f(u[2*lane]), vb = bfbits2f(u[2*lane+1]);
  bool bad = !(fabsf(va) <= 1000.0f) || !(fabsf(vb) <= 1000.0f);
  return (__ballot(bad) == 0ull) ? 1 : 0;
}
__device__ __forceinline__ void WSYNC(){ __builtin_amdgcn_wave_barrier(); }

// async global->LDS DMA: data never touches VGPRs. LDS dest wave-uniform,
// +lane*size implicit; global src per-lane.
__device__ __forceinline__ void gl_lds4(const void* g, void* l){
  __builtin_amdgcn_global_load_lds(
      (const __attribute__((address_space(1))) unsigned*)g,
      (__attribute__((address_space(3))) unsigned*)l, 4, 0, 0);
}

// ============ S1: fused {detect, cvt, weight-swizzle, degree-hist} ============
__global__ void k_setup1(const void* __restrict__ pos, const void* __restrict__ Wemb,
                         const void* __restrict__ Wsc, const void* __restrict__ wprod,
                         const void* __restrict__ wro0, const void* __restrict__ Wro1a,
                         const void* __restrict__ wro1b, const void* __restrict__ Wr1,
                         const void* __restrict__ Wr2, const void* __restrict__ Wr3,
                         const int* __restrict__ dstp, float* __restrict__ cv,
                         short* __restrict__ swz, int* __restrict__ deg){
  int b = blockIdx.x, tix = threadIdx.x;
  if (b >= B_CVT + B_SWZ){            // ---- degree histogram ----
    int e = (b - B_CVT - B_SWZ)*256 + tix;
    atomicAdd(&deg[dstp[e]], 1);
    return;
  }
  int fl = detect_fl(pos);
  if (b < B_CVT){                      // ---- fp32 conversion ----
    int i = b*256 + tix;
    if (i < 24576){ cv[CV_POS + i] = ldf(pos, i, fl); return; }
    if (i < 24832){ int j=i-24576; cv[CV_EMB + j] = ldf(Wemb, j, fl); return; }
    if (i < 57600){ int j=i-24832; cv[CV_SC  + j] = ldf(Wsc,  j, fl); return; }
    if (i < 57632){ int j=i-57600; cv[CV_PROD+ j] = ldf(wprod,j, fl); return; }
    if (i < 57696){ int j=i-57632; cv[CV_RO0 + j] = ldf(wro0, j, fl); return; }
    if (i < 58720){ int j=i-57696; cv[CV_RO1A+ j] = ldf(Wro1a,j, fl); return; }
    if (i < CVT_WORK){ int j=i-58720; cv[CV_RO1B+ j] = ldf(wro1b,j, fl); return; }
    return;
  }
  // ---- MFMA B-fragment-order bf16 weights, read directly from raw inputs ----
  int i = (b - B_CVT)*256 + tix;       // 20480 exact
  int l = i / SWZ_PER_L, w = i % SWZ_PER_L;
  float v;
  if (w < 2048){
    int t = w >> 9, q = (w >> 7) & 3, n = (w >> 3) & 15, j = w & 7;
    int k = q*8 + j;
    v = (k < 8) ? ldf(Wr1, l*512 + k*64 + t*16 + n, fl) : 0.0f;
  } else if (w < 6144){
    int w2 = w - 2048;
    int nt = w2 >> 10, kt = (w2 >> 9) & 1, q = (w2 >> 7) & 3, n = (w2 >> 3) & 15, j = w2 & 7;
    int k = kt*32 + q*8 + j;
    v = ldf(Wr2, l*4096 + k*64 + nt*16 + n, fl);
  } else {
    int w3 = w - 6144;
    int nt = w3 >> 10, kt = (w3 >> 9) & 1, q = (w3 >> 7) & 3, n = (w3 >> 3) & 15, j = w3 & 7;
    int k = kt*32 + q*8 + j;
    v = ldf(Wr3, l*4096 + k*64 + nt*16 + n, fl);
  }
  swz[i] = f2bs(v);
}

// ============ S2: prefix-scan + ene-zero (1 block; hinit eliminated:
//               gu<0> reads embeddings from registers) ============
__global__ void k_scan(const int* __restrict__ deg, int* __restrict__ row_start,
                       int* __restrict__ cursor, float* __restrict__ ene){
  __shared__ int lds[1024];
  int t = threadIdx.x;
  if (t < NGRP) ene[t] = 0.0f;
  int v[8]; int tot = 0;
#pragma unroll
  for (int k = 0; k < 8; k++){ v[k] = deg[t*8+k]; tot += v[k]; }
  lds[t] = tot; __syncthreads();
  for (int off = 1; off < 1024; off <<= 1){
    int x = (t >= off) ? lds[t-off] : 0;
    __syncthreads();
    lds[t] += x;
    __syncthreads();
  }
  int base = lds[t] - tot;
#pragma unroll
  for (int k = 0; k < 8; k++){ row_start[t*8+k] = base; cursor[t*8+k] = base; base += v[k]; }
  if (t == 1023) row_start[N_NODES] = base;
}

// ============ S3: fused {CSR fill, edge geometry, src-type} ============
__global__ void k_fillgeom(const int* __restrict__ ei, int* __restrict__ cursor,
                           const float* __restrict__ posf, const int* __restrict__ types,
                           int* __restrict__ sslot, unsigned char* __restrict__ tsl,
                           unsigned short* __restrict__ Yb, float* __restrict__ rbuf){
  int e = blockIdx.x*256 + threadIdx.x;
  int s = ei[e], d = ei[N_EDGES + e];
  int slot = atomicAdd(&cursor[d], 1);
  sslot[slot] = s;
  tsl[slot] = (unsigned char)types[s];
  float vx = posf[d*3+0] - posf[s*3+0];
  float vy = posf[d*3+1] - posf[s*3+1];
  float vz = posf[d*3+2] - posf[s*3+2];
  float r = sqrtf(vx*vx + vy*vy + vz*vz + 1e-12f);
  float ir = 1.0f / r;
  float x = vx*ir, y = vy*ir, z = vz*ir;
  const float s3 = 1.7320508075688772f, s15 = 3.872983346207417f, s5 = 2.23606797749979f;
  const float s105 = 10.246950765959598f, s7 = 2.6457513110645907f;
  const float c35 = 2.091650066335189f, c21 = 1.6201851746019651f;
  float x2 = x*x, y2 = y*y, z2 = z*z;
  float ys[16] = {
    1.0f, s3*x, s3*y, s3*z,
    s15*x*y, s15*y*z, 0.5f*s5*(3.0f*z2-1.0f), s15*x*z,
    0.5f*s15*(x2-y2), c35*y*(3.0f*x2-y2), s105*x*y*z, c21*y*(5.0f*z2-1.0f),
    0.5f*s7*(5.0f*z2*z-3.0f*z), c21*x*(5.0f*z2-1.0f), 0.5f*s105*z*(x2-y2),
    c35*x*(x2-3.0f*y2) };
  union { bf16 b[16]; uint4 u[2]; } pk;
#pragma unroll
  for (int k = 0; k < 16; k++) pk.b[k] = __float2bfloat16(ys[k]);
  uint4* yp = (uint4*)(Yb + (size_t)slot*16);
  yp[0] = pk.u[0];
  yp[1] = pk.u[1];
  rbuf[slot] = r;
}

// ====== fused node kernel: wave-independent 16-slot chunks; per chunk
//        {Y(/h) DMA issue -> wave-PRIVATE MFMA radial MLP (hides DMA) ->
//         vmcnt(0) -> accumulate reading Rw straight from scratch A}.
//        NO block barriers in the loop. LAYER_KIND 0: h[src]=Wemb[type[src]]
//        from 4 registers (no gather, no h buffer); sc-term from wemb row. ======
#define ROWS 72
template<int LAYER_KIND>
__global__ void __launch_bounds__(256) k_gu(const short* __restrict__ sw,
        const float* __restrict__ rbuf, const unsigned char* __restrict__ tsl,
        const int* __restrict__ sslot, const float* __restrict__ h_old,
        float* __restrict__ h_new, const unsigned short* __restrict__ Yb,
        const int* __restrict__ row_start, const int* __restrict__ types,
        const float* __restrict__ Wsc, const float* __restrict__ wprod,
        const float* __restrict__ wemb, const float* __restrict__ wro0,
        const float* __restrict__ Wro1a, const float* __restrict__ wro1b,
        const int* __restrict__ batch, float* __restrict__ ene){
  __shared__ __align__(16) short A_[4][16*ROWS];                 // 9 KB scratch/Rw
  __shared__ __align__(16) float hS[LAYER_KIND ? 4 : 1][16][64]; // 16 KB (L1 only)
  __shared__ __align__(16) unsigned short yS[4][16][16];         // 2 KB
  __shared__ float ebins[NGRP];
  __shared__ float hn_l[LAYER_KIND ? 4 : 1][64];
  int tix = threadIdx.x;
  if (tix < NGRP) ebins[tix] = 0.0f;
  __syncthreads();
  int wv = tix >> 6, lane = tix & 63;
  int q = lane >> 4, nn = lane & 15;
  int n = blockIdx.x * 4 + wv;
  int beg = row_start[n], end = row_start[n + 1];
  short* A = A_[wv];

  const bf16x8* S1 = (const bf16x8*)(sw);
  const bf16x8* S2 = (const bf16x8*)(sw + 2048);
  const bf16x8* S3 = (const bf16x8*)(sw + 6144);

  // layer-0 embedding rows (4 types x 64 ch) in registers
  float e0=0.f, e1=0.f, e2=0.f, e3=0.f;
  if (LAYER_KIND == 0){
    e0 = wemb[lane]; e1 = wemb[64+lane]; e2 = wemb[128+lane]; e3 = wemb[192+lane];
  }

  float acc[16];
#pragma unroll
  for (int s = 0; s < 16; s++) acc[s] = 0.0f;

  for (int cb = beg; cb < end; cb += 16){
    int cnt = min(16, end - cb);
    WSYNC();   // fence: prior chunk's LDS reads precede this chunk's DMA/MLP
    // ---------- phase A: issue DMAs ----------
    const char* ysrc = (const char*)Yb + (size_t)cb*32 + lane*4;
    gl_lds4(ysrc,       &yS[wv][0][0]);
    gl_lds4(ysrc + 256, &yS[wv][8][0]);
    int tv = 0;
    if (LAYER_KIND == 0){
      tv = (int)tsl[min(cb + nn, N_EDGES - 1)];   // chunk types -> register
    } else {
      int sv = sslot[min(cb + nn, N_EDGES - 1)];
      for (int i = 0; i < cnt; i++){
        int src = __builtin_amdgcn_readlane(sv, i);
        gl_lds4(h_old + (size_t)src*64 + lane, &hS[wv][i][0]);
      }
    }
    // ---------- phase B: wave-private MFMA radial MLP (hides DMA) ----------
    {
      float r = rbuf[min(cb + nn, N_EDGES - 1)];
      float xc = r * 0.2f;
      float f = 0.0f;
      if (xc < 1.0f){
        float x3 = xc*xc*xc, x6 = x3*x3, x7 = x6*xc, x8 = x7*xc;
        f = 1.0f - 28.0f*x6 + 48.0f*x7 - 21.0f*x8;
      }
      float bs = 0.6324555320336759f * f / r;
      float t0 = PI_F * r * 0.2f;
      bf16x8 af1 = {0,0,0,0,0,0,0,0};
      if (q == 0){
#pragma unroll
        for (int j = 0; j < 8; j++) af1[j] = f2bs(bs * __sinf((float)(j+1) * t0));
      }
      f32x4 macc[4];
#pragma unroll
      for (int t = 0; t < 4; t++){
        bf16x8 b = S1[t*64 + q*16 + nn];
        f32x4 z = {0.f,0.f,0.f,0.f};
        macc[t] = __builtin_amdgcn_mfma_f32_16x16x32_bf16(af1, b, z, 0, 0, 0);
      }
#pragma unroll
      for (int t = 0; t < 4; t++)
#pragma unroll
        for (int rg = 0; rg < 4; rg++)
          A[(q*4+rg)*ROWS + t*16 + nn] = f2bs(silu_f(macc[t][rg]));
      WSYNC();
      bf16x8 a0 = *(const bf16x8*)&A[nn*ROWS + 0*32 + q*8];
      bf16x8 a1 = *(const bf16x8*)&A[nn*ROWS + 1*32 + q*8];
      WSYNC();
#pragma unroll
      for (int t = 0; t < 4; t++){
        f32x4 z = {0.f,0.f,0.f,0.f};
        bf16x8 b0 = S2[t*128 + 0*64 + q*16 + nn];
        bf16x8 b1 = S2[t*128 + 1*64 + q*16 + nn];
        z = __builtin_amdgcn_mfma_f32_16x16x32_bf16(a0, b0, z, 0, 0, 0);
        z = __builtin_amdgcn_mfma_f32_16x16x32_bf16(a1, b1, z, 0, 0, 0);
        macc[t] = z;
      }
#pragma unroll
      for (int t = 0; t < 4; t++)
#pragma unroll
        for (int rg = 0; rg < 4; rg++)
          A[(q*4+rg)*ROWS + t*16 + nn] = f2bs(silu_f(macc[t][rg]));
      WSYNC();
      a0 = *(const bf16x8*)&A[nn*ROWS + 0*32 + q*8];
      a1 = *(const bf16x8*)&A[nn*ROWS + 1*32 + q*8];
      WSYNC();
#pragma unroll
      for (int t = 0; t < 4; t++){
        f32x4 z = {0.f,0.f,0.f,0.f};
        bf16x8 b0 = S3[t*128 + 0*64 + q*16 + nn];
        bf16x8 b1 = S3[t*128 + 1*64 + q*16 + nn];
        z = __builtin_amdgcn_mfma_f32_16x16x32_bf16(a0, b0, z, 0, 0, 0);
        z = __builtin_amdgcn_mfma_f32_16x16x32_bf16(a1, b1, z, 0, 0, 0);
        macc[t] = z;
      }
      // final Rw stays in A: layout A[slot*ROWS + ch]
#pragma unroll
      for (int t = 0; t < 4; t++)
#pragma unroll
        for (int rg = 0; rg < 4; rg++)
          A[(q*4+rg)*ROWS + t*16 + nn] = f2bs(macc[t][rg]);
      WSYNC();
    }
    // ---------- phase C: wait DMAs, accumulate (all wave-private) ----------
    asm volatile("s_waitcnt vmcnt(0)" ::: "memory");
    __builtin_amdgcn_sched_barrier(0);
    for (int i = 0; i < cnt; i++){
      float rw = bfbits2f((unsigned short)A[i*ROWS + lane]);  // 2-way alias: free
      float hv;
      if (LAYER_KIND == 0){
        int ty = __builtin_amdgcn_readlane(tv, i);
        hv = (ty & 2) ? ((ty & 1) ? e3 : e2) : ((ty & 1) ? e1 : e0);
      } else {
        hv = hS[wv][i][lane];
      }
      float g = rw * hv;
      const uint4* yq = (const uint4*)&yS[wv][i][0];   // uniform -> broadcast
      uint4 ya = yq[0], yb = yq[1];
      float lo, hi;
      unpack2(ya.x, lo, hi); acc[0]  += g*lo; acc[1]  += g*hi;
      unpack2(ya.y, lo, hi); acc[2]  += g*lo; acc[3]  += g*hi;
      unpack2(ya.z, lo, hi); acc[4]  += g*lo; acc[5]  += g*hi;
      unpack2(ya.w, lo, hi); acc[6]  += g*lo; acc[7]  += g*hi;
      unpack2(yb.x, lo, hi); acc[8]  += g*lo; acc[9]  += g*hi;
      unpack2(yb.y, lo, hi); acc[10] += g*lo; acc[11] += g*hi;
      unpack2(yb.z, lo, hi); acc[12] += g*lo; acc[13] += g*hi;
      unpack2(yb.w, lo, hi); acc[14] += g*lo; acc[15] += g*hi;
    }
  }
#pragma unroll
  for (int s = 0; s < 16; s++) acc[s] *= INV_AVG;

  int ty = __builtin_amdgcn_readfirstlane(types[n]);
  const float* Ws = Wsc + (size_t)ty*4096;
  // node's own h row: layer 0 -> embedding row (h0 buffer eliminated)
  const float* hrow = (LAYER_KIND == 0) ? (wemb + ty*64) : (h_old + (size_t)n*64);
  float sc0 = 0.f, sc1 = 0.f, sc2 = 0.f, sc3 = 0.f;
#pragma unroll
  for (int c = 0; c < 64; c += 4){
    sc0 += hrow[c+0] * Ws[(c+0)*64 + lane];
    sc1 += hrow[c+1] * Ws[(c+1)*64 + lane];
    sc2 += hrow[c+2] * Ws[(c+2)*64 + lane];
    sc3 += hrow[c+3] * Ws[(c+3)*64 + lane];
  }
  float sc = (sc0 + sc1) + (sc2 + sc3);

  float inv0 = acc[0];
  float inv1 = acc[1]*acc[1] + acc[2]*acc[2] + acc[3]*acc[3];
  float inv2 = acc[4]*acc[4] + acc[5]*acc[5] + acc[6]*acc[6] + acc[7]*acc[7]
             + acc[8]*acc[8];
  float inv3 = acc[9]*acc[9] + acc[10]*acc[10] + acc[11]*acc[11] + acc[12]*acc[12]
             + acc[13]*acc[13] + acc[14]*acc[14] + acc[15]*acc[15];
  const float* wp = wprod + ty*4;
  float hn = inv0*wp[0] + inv1*wp[1] + inv2*wp[2] + inv3*wp[3] + sc;
  if (LAYER_KIND == 0)
    h_new[(size_t)n*64 + lane] = hn;   // layer-1 output is consumed in-kernel only

  float ev;
  if (LAYER_KIND == 0){
    float p = hn * wro0[lane];
#pragma unroll
    for (int off = 32; off >= 1; off >>= 1) p += __shfl_xor(p, off, 64);
    ev = p;
  } else {
    hn_l[wv][lane] = hn;
    int j = lane & 15;
    float pj = 0.0f;
#pragma unroll
    for (int c = 0; c < 64; c++)
      pj += hn_l[wv][c] * Wro1a[c*16 + j];
    float evj = silu_f(pj) * wro1b[j];
    evj += __shfl_xor(evj, 8, 64);
    evj += __shfl_xor(evj, 4, 64);
    evj += __shfl_xor(evj, 2, 64);
    evj += __shfl_xor(evj, 1, 64);
    ev = evj;
  }
  if (lane == 0) atomicAdd(&ebins[batch[n]], ev);
  __syncthreads();
  if (tix < NGRP){
    float v = ebins[tix];
    if (v != 0.0f) atomicAdd(&ene[tix], v);
  }
}

// ---------------- final output convert (format matches detected input) ----
__global__ void k_out(const float* __restrict__ ene, const void* __restrict__ pos,
                      void* __restrict__ out){
  int fl = detect_fl(pos);
  int t = threadIdx.x;
  if (t < NGRP){
    if (fl) ((bf16*)out)[t] = __float2bfloat16(ene[t]);
    else    ((float*)out)[t] = ene[t];
  }
}

static inline size_t rup(size_t x){ return (x + 255) & ~(size_t)255; }

extern "C" void kernel_launch(void* const* d_in, const int* in_sizes, int n_in,
                              void* d_out, int out_size, void* d_ws, size_t ws_size,
                              hipStream_t stream) {
  const void* pos   = d_in[0];
  const int*  types = (const int*)d_in[1];
  const int*  ei    = (const int*)d_in[2];
  const int*  batch = (const int*)d_in[3];
  const void* Wemb  = d_in[4];
  const void* Wr1   = d_in[5];
  const void* Wr2   = d_in[6];
  const void* Wr3   = d_in[7];
  const void* Wsc   = d_in[8];
  const void* wprod = d_in[9];
  const void* wro0  = d_in[10];
  const void* Wro1a = d_in[11];
  const void* wro1b = d_in[12];

  char* w = (char*)d_ws;
  float* cv       = (float*)w; w += rup((size_t)CVT_N*4);
  short* swz      = (short*)w; w += rup((size_t)SWZ_N*2);
  float* ene      = (float*)w; w += 256;
  int*   deg      = (int*)  w; w += rup((size_t)N_NODES*4);
  int*   row_start= (int*)  w; w += rup((size_t)(N_NODES+1)*4);
  int*   cursor   = (int*)  w; w += rup((size_t)N_NODES*4);
  int*   sslot    = (int*)  w; w += rup((size_t)N_EDGES*4);
  unsigned char* tsl = (unsigned char*)w; w += rup((size_t)N_EDGES);
  float* hbuf     = (float*)w; w += rup((size_t)N_NODES*64*4);
  float* rbuf     = (float*)w; w += rup((size_t)N_EDGES*4);
  unsigned short* Yb = (unsigned short*)w; w += rup((size_t)N_EDGES*16*2);
  w += 4096;   // DMA over-read slack (tail Y chunks read <=480B past Yb end)

  hipMemsetAsync(deg, 0, N_NODES*4, stream);

  const int* dstp = ei + N_EDGES;
  k_setup1<<<B_CVT + B_SWZ + B_HIST, 256, 0, stream>>>(
      pos, Wemb, Wsc, wprod, wro0, Wro1a, wro1b, Wr1, Wr2, Wr3, dstp, cv, swz, deg);
  k_scan<<<1, 1024, 0, stream>>>(deg, row_start, cursor, ene);
  k_fillgeom<<<N_EDGES/256, 256, 0, stream>>>(ei, cursor, cv + CV_POS, types,
      sslot, tsl, Yb, rbuf);

  k_gu<0><<<N_NODES/4, 256, 0, stream>>>(swz, rbuf, tsl, sslot,
      hbuf /*unused*/, hbuf /*h_new*/, Yb, row_start, types,
      cv + CV_SC, cv + CV_PROD, cv + CV_EMB,
      cv + CV_RO0, cv + CV_RO1A, cv + CV_RO1B, batch, ene);
  k_gu<1><<<N_NODES/4, 256, 0, stream>>>(swz + SWZ_PER_L, rbuf, tsl, sslot,
      hbuf /*h_old*/, hbuf /*unused*/, Yb, row_start, types,
      cv + CV_SC + (size_t)NELM*4096, cv + CV_PROD + NELM*4, cv + CV_EMB,
      cv + CV_RO0, cv + CV_RO1A, cv + CV_RO1B, batch, ene);

  k_out<<<1, 64, 0, stream>>>(ene, pos, d_out);
}

// Round 8
// 191.041 us; speedup vs baseline: 1.3868x; 1.0505x over previous
//
#include <hip/hip_runtime.h>
#include <hip/hip_bf16.h>
#include <math.h>

#define N_NODES 8192
#define N_EDGES 131072
#define NGRP 16
#define NLAY 2
#define NELM 4
constexpr float INV_AVG = 1.0f / 16.0f;
constexpr float PI_F = 3.14159265358979323846f;

// converted fp32 buffer layout (element offsets).
#define CV_POS   0        // 24576
#define CV_EMB   24576    // 256
#define CV_SC    42240    // 32768 (natural [l][ty][c:64][d:64])
#define CV_PROD  75008    // 32
#define CV_RO0   75040    // 64
#define CV_RO1A  75104    // 1024
#define CV_RO1B  76128    // 16
#define CVT_N    76144

// swizzled bf16 MFMA B-fragment weight buffer: per layer 10240 shorts
#define SWZ_PER_L 10240
#define SWZ_N     20480

// setup1 fused-dispatch block ranges
#define B_CVT  230
#define B_SWZ  80
#define B_HIST 512
#define CVT_WORK 58736

typedef __hip_bfloat16 bf16;
typedef __attribute__((ext_vector_type(8))) short bf16x8;
typedef __attribute__((ext_vector_type(4))) float f32x4;

__device__ __forceinline__ float silu_f(float x){ return x / (1.0f + __expf(-x)); }
__device__ __forceinline__ float bfbits2f(unsigned short u){
  return __uint_as_float(((unsigned)u) << 16);
}
__device__ __forceinline__ void unpack2(unsigned u, float& lo, float& hi){
  lo = __uint_as_float(u << 16);
  hi = __uint_as_float(u & 0xffff0000u);
}
__device__ __forceinline__ short f2bs(float v){
  union { bf16 b; short s; } u; u.b = __float2bfloat16(v); return u.s;
}
__device__ __forceinline__ float ldf(const void* p, int i, int flag){
  if (flag) return bfbits2f(((const unsigned short*)p)[i]);
  return ((const float*)p)[i];
}
// per-wave input dtype detection (reads first 128 ushorts of pos; L1/L2-hot).
__device__ __forceinline__ int detect_fl(const void* pos){
  int lane = threadIdx.x & 63;
  const unsigned short* u = (const unsigned short*)pos;
  float va = bfbits2f(u[2*lane]), vb = bfbits2f(u[2*lane+1]);
  bool bad = !(fabsf(va) <= 1000.0f) || !(fabsf(vb) <= 1000.0f);
  return (__ballot(bad) == 0ull) ? 1 : 0;
}
__device__ __forceinline__ void WSYNC(){ __builtin_amdgcn_wave_barrier(); }

// async global->LDS DMA: data never touches VGPRs. LDS dest wave-uniform,
// +lane*size implicit; global src per-lane.
__device__ __forceinline__ void gl_lds4(const void* g, void* l){
  __builtin_amdgcn_global_load_lds(
      (const __attribute__((address_space(1))) unsigned*)g,
      (__attribute__((address_space(3))) unsigned*)l, 4, 0, 0);
}

// ============ S1: fused {detect, cvt, weight-swizzle, degree-hist} ============
__global__ void k_setup1(const void* __restrict__ pos, const void* __restrict__ Wemb,
                         const void* __restrict__ Wsc, const void* __restrict__ wprod,
                         const void* __restrict__ wro0, const void* __restrict__ Wro1a,
                         const void* __restrict__ wro1b, const void* __restrict__ Wr1,
                         const void* __restrict__ Wr2, const void* __restrict__ Wr3,
                         const int* __restrict__ dstp, float* __restrict__ cv,
                         short* __restrict__ swz, int* __restrict__ deg){
  int b = blockIdx.x, tix = threadIdx.x;
  if (b >= B_CVT + B_SWZ){            // ---- degree histogram ----
    int e = (b - B_CVT - B_SWZ)*256 + tix;
    atomicAdd(&deg[dstp[e]], 1);
    return;
  }
  int fl = detect_fl(pos);
  if (b < B_CVT){                      // ---- fp32 conversion ----
    int i = b*256 + tix;
    if (i < 24576){ cv[CV_POS + i] = ldf(pos, i, fl); return; }
    if (i < 24832){ int j=i-24576; cv[CV_EMB + j] = ldf(Wemb, j, fl); return; }
    if (i < 57600){ int j=i-24832; cv[CV_SC  + j] = ldf(Wsc,  j, fl); return; }
    if (i < 57632){ int j=i-57600; cv[CV_PROD+ j] = ldf(wprod,j, fl); return; }
    if (i < 57696){ int j=i-57632; cv[CV_RO0 + j] = ldf(wro0, j, fl); return; }
    if (i < 58720){ int j=i-57696; cv[CV_RO1A+ j] = ldf(Wro1a,j, fl); return; }
    if (i < CVT_WORK){ int j=i-58720; cv[CV_RO1B+ j] = ldf(wro1b,j, fl); return; }
    return;
  }
  // ---- MFMA B-fragment-order bf16 weights, read directly from raw inputs ----
  int i = (b - B_CVT)*256 + tix;       // 20480 exact
  int l = i / SWZ_PER_L, w = i % SWZ_PER_L;
  float v;
  if (w < 2048){
    int t = w >> 9, q = (w >> 7) & 3, n = (w >> 3) & 15, j = w & 7;
    int k = q*8 + j;
    v = (k < 8) ? ldf(Wr1, l*512 + k*64 + t*16 + n, fl) : 0.0f;
  } else if (w < 6144){
    int w2 = w - 2048;
    int nt = w2 >> 10, kt = (w2 >> 9) & 1, q = (w2 >> 7) & 3, n = (w2 >> 3) & 15, j = w2 & 7;
    int k = kt*32 + q*8 + j;
    v = ldf(Wr2, l*4096 + k*64 + nt*16 + n, fl);
  } else {
    int w3 = w - 6144;
    int nt = w3 >> 10, kt = (w3 >> 9) & 1, q = (w3 >> 7) & 3, n = (w3 >> 3) & 15, j = w3 & 7;
    int k = kt*32 + q*8 + j;
    v = ldf(Wr3, l*4096 + k*64 + nt*16 + n, fl);
  }
  swz[i] = f2bs(v);
}

// ============ S2: prefix-scan + ene2-zero (1 block) ============
__global__ void k_scan(const int* __restrict__ deg, int* __restrict__ row_start,
                       int* __restrict__ cursor, float* __restrict__ ene2){
  __shared__ int lds[1024];
  int t = threadIdx.x;
  if (t < 8*NGRP) ene2[t] = 0.0f;
  int v[8]; int tot = 0;
#pragma unroll
  for (int k = 0; k < 8; k++){ v[k] = deg[t*8+k]; tot += v[k]; }
  lds[t] = tot; __syncthreads();
  for (int off = 1; off < 1024; off <<= 1){
    int x = (t >= off) ? lds[t-off] : 0;
    __syncthreads();
    lds[t] += x;
    __syncthreads();
  }
  int base = lds[t] - tot;
#pragma unroll
  for (int k = 0; k < 8; k++){ row_start[t*8+k] = base; cursor[t*8+k] = base; base += v[k]; }
  if (t == 1023) row_start[N_NODES] = base;
}

// ============ S3: fused {CSR fill, edge geometry, src-type} ============
__global__ void k_fillgeom(const int* __restrict__ ei, int* __restrict__ cursor,
                           const float* __restrict__ posf, const int* __restrict__ types,
                           int* __restrict__ sslot, unsigned char* __restrict__ tsl,
                           unsigned short* __restrict__ Yb, float* __restrict__ rbuf){
  int e = blockIdx.x*256 + threadIdx.x;
  int s = ei[e], d = ei[N_EDGES + e];
  int slot = atomicAdd(&cursor[d], 1);
  sslot[slot] = s;
  tsl[slot] = (unsigned char)types[s];
  float vx = posf[d*3+0] - posf[s*3+0];
  float vy = posf[d*3+1] - posf[s*3+1];
  float vz = posf[d*3+2] - posf[s*3+2];
  float r = sqrtf(vx*vx + vy*vy + vz*vz + 1e-12f);
  float ir = 1.0f / r;
  float x = vx*ir, y = vy*ir, z = vz*ir;
  const float s3 = 1.7320508075688772f, s15 = 3.872983346207417f, s5 = 2.23606797749979f;
  const float s105 = 10.246950765959598f, s7 = 2.6457513110645907f;
  const float c35 = 2.091650066335189f, c21 = 1.6201851746019651f;
  float x2 = x*x, y2 = y*y, z2 = z*z;
  float ys[16] = {
    1.0f, s3*x, s3*y, s3*z,
    s15*x*y, s15*y*z, 0.5f*s5*(3.0f*z2-1.0f), s15*x*z,
    0.5f*s15*(x2-y2), c35*y*(3.0f*x2-y2), s105*x*y*z, c21*y*(5.0f*z2-1.0f),
    0.5f*s7*(5.0f*z2*z-3.0f*z), c21*x*(5.0f*z2-1.0f), 0.5f*s105*z*(x2-y2),
    c35*x*(x2-3.0f*y2) };
  union { bf16 b[16]; uint4 u[2]; } pk;
#pragma unroll
  for (int k = 0; k < 16; k++) pk.b[k] = __float2bfloat16(ys[k]);
  uint4* yp = (uint4*)(Yb + (size_t)slot*16);
  yp[0] = pk.u[0];
  yp[1] = pk.u[1];
  rbuf[slot] = r;
}

// ====== fused node kernel, ONE WAVE PER BLOCK (node = blockIdx.x) ======
// Per 16-slot chunk: {Y(/h) DMA issue -> wave-private MFMA radial MLP (hides
// DMA) -> vmcnt(0) -> accumulate reading Rw straight from scratch A}.
// No __syncthreads anywhere; energy via contention-spread ene2[n&7][g].
#define ROWS 72
template<int LAYER_KIND>
__global__ void __launch_bounds__(64, 4) k_gu(const short* __restrict__ sw,
        const float* __restrict__ rbuf, const unsigned char* __restrict__ tsl,
        const int* __restrict__ sslot, const float* __restrict__ h_old,
        float* __restrict__ h_new, const unsigned short* __restrict__ Yb,
        const int* __restrict__ row_start, const int* __restrict__ types,
        const float* __restrict__ Wsc, const float* __restrict__ wprod,
        const float* __restrict__ wemb, const float* __restrict__ wro0,
        const float* __restrict__ Wro1a, const float* __restrict__ wro1b,
        const int* __restrict__ batch, float* __restrict__ ene2){
  __shared__ __align__(16) short A_[16*ROWS];                    // 2.25 KB
  __shared__ __align__(16) float hS[LAYER_KIND ? 16 : 1][64];    // 4 KB (L1)
  __shared__ __align__(16) unsigned short yS[16][16];            // 0.5 KB
  __shared__ float hn_l[64];
  int lane = threadIdx.x;
  int q = lane >> 4, nn = lane & 15;
  int n = blockIdx.x;
  int beg = row_start[n], end = row_start[n + 1];
  short* A = A_;

  const bf16x8* S1 = (const bf16x8*)(sw);
  const bf16x8* S2 = (const bf16x8*)(sw + 2048);
  const bf16x8* S3 = (const bf16x8*)(sw + 6144);

  // layer-0 embedding rows (4 types x 64 ch) in registers
  float e0=0.f, e1=0.f, e2=0.f, e3=0.f;
  if (LAYER_KIND == 0){
    e0 = wemb[lane]; e1 = wemb[64+lane]; e2 = wemb[128+lane]; e3 = wemb[192+lane];
  }

  float acc[16];
#pragma unroll
  for (int s = 0; s < 16; s++) acc[s] = 0.0f;

  for (int cb = beg; cb < end; cb += 16){
    int cnt = min(16, end - cb);
    WSYNC();   // fence: prior chunk's LDS reads precede this chunk's DMA/MLP
    // ---------- phase A: issue DMAs ----------
    const char* ysrc = (const char*)Yb + (size_t)cb*32 + lane*4;
    gl_lds4(ysrc,       &yS[0][0]);
    gl_lds4(ysrc + 256, &yS[8][0]);
    int tv = 0;
    if (LAYER_KIND == 0){
      tv = (int)tsl[min(cb + nn, N_EDGES - 1)];   // chunk types -> register
    } else {
      int sv = sslot[min(cb + nn, N_EDGES - 1)];
      for (int i = 0; i < cnt; i++){
        int src = __builtin_amdgcn_readlane(sv, i);
        gl_lds4(h_old + (size_t)src*64 + lane, &hS[i][0]);
      }
    }
    // ---------- phase B: wave-private MFMA radial MLP (hides DMA) ----------
    {
      float r = rbuf[min(cb + nn, N_EDGES - 1)];
      float xc = r * 0.2f;
      float f = 0.0f;
      if (xc < 1.0f){
        float x3 = xc*xc*xc, x6 = x3*x3, x7 = x6*xc, x8 = x7*xc;
        f = 1.0f - 28.0f*x6 + 48.0f*x7 - 21.0f*x8;
      }
      float bs = 0.6324555320336759f * f / r;
      float t0 = PI_F * r * 0.2f;
      bf16x8 af1 = {0,0,0,0,0,0,0,0};
      if (q == 0){
#pragma unroll
        for (int j = 0; j < 8; j++) af1[j] = f2bs(bs * __sinf((float)(j+1) * t0));
      }
      f32x4 macc[4];
#pragma unroll
      for (int t = 0; t < 4; t++){
        bf16x8 b = S1[t*64 + q*16 + nn];
        f32x4 z = {0.f,0.f,0.f,0.f};
        macc[t] = __builtin_amdgcn_mfma_f32_16x16x32_bf16(af1, b, z, 0, 0, 0);
      }
#pragma unroll
      for (int t = 0; t < 4; t++)
#pragma unroll
        for (int rg = 0; rg < 4; rg++)
          A[(q*4+rg)*ROWS + t*16 + nn] = f2bs(silu_f(macc[t][rg]));
      WSYNC();
      bf16x8 a0 = *(const bf16x8*)&A[nn*ROWS + 0*32 + q*8];
      bf16x8 a1 = *(const bf16x8*)&A[nn*ROWS + 1*32 + q*8];
      WSYNC();
#pragma unroll
      for (int t = 0; t < 4; t++){
        f32x4 z = {0.f,0.f,0.f,0.f};
        bf16x8 b0 = S2[t*128 + 0*64 + q*16 + nn];
        bf16x8 b1 = S2[t*128 + 1*64 + q*16 + nn];
        z = __builtin_amdgcn_mfma_f32_16x16x32_bf16(a0, b0, z, 0, 0, 0);
        z = __builtin_amdgcn_mfma_f32_16x16x32_bf16(a1, b1, z, 0, 0, 0);
        macc[t] = z;
      }
#pragma unroll
      for (int t = 0; t < 4; t++)
#pragma unroll
        for (int rg = 0; rg < 4; rg++)
          A[(q*4+rg)*ROWS + t*16 + nn] = f2bs(silu_f(macc[t][rg]));
      WSYNC();
      a0 = *(const bf16x8*)&A[nn*ROWS + 0*32 + q*8];
      a1 = *(const bf16x8*)&A[nn*ROWS + 1*32 + q*8];
      WSYNC();
#pragma unroll
      for (int t = 0; t < 4; t++){
        f32x4 z = {0.f,0.f,0.f,0.f};
        bf16x8 b0 = S3[t*128 + 0*64 + q*16 + nn];
        bf16x8 b1 = S3[t*128 + 1*64 + q*16 + nn];
        z = __builtin_amdgcn_mfma_f32_16x16x32_bf16(a0, b0, z, 0, 0, 0);
        z = __builtin_amdgcn_mfma_f32_16x16x32_bf16(a1, b1, z, 0, 0, 0);
        macc[t] = z;
      }
      // final Rw stays in A: layout A[slot*ROWS + ch]
#pragma unroll
      for (int t = 0; t < 4; t++)
#pragma unroll
        for (int rg = 0; rg < 4; rg++)
          A[(q*4+rg)*ROWS + t*16 + nn] = f2bs(macc[t][rg]);
      WSYNC();
    }
    // ---------- phase C: wait DMAs, accumulate (all wave-private) ----------
    asm volatile("s_waitcnt vmcnt(0)" ::: "memory");
    __builtin_amdgcn_sched_barrier(0);
    for (int i = 0; i < cnt; i++){
      float rw = bfbits2f((unsigned short)A[i*ROWS + lane]);  // 2-way alias: free
      float hv;
      if (LAYER_KIND == 0){
        int ty = __builtin_amdgcn_readlane(tv, i);
        hv = (ty & 2) ? ((ty & 1) ? e3 : e2) : ((ty & 1) ? e1 : e0);
      } else {
        hv = hS[i][lane];
      }
      float g = rw * hv;
      const uint4* yq = (const uint4*)&yS[i][0];   // uniform -> broadcast
      uint4 ya = yq[0], yb = yq[1];
      float lo, hi;
      unpack2(ya.x, lo, hi); acc[0]  += g*lo; acc[1]  += g*hi;
      unpack2(ya.y, lo, hi); acc[2]  += g*lo; acc[3]  += g*hi;
      unpack2(ya.z, lo, hi); acc[4]  += g*lo; acc[5]  += g*hi;
      unpack2(ya.w, lo, hi); acc[6]  += g*lo; acc[7]  += g*hi;
      unpack2(yb.x, lo, hi); acc[8]  += g*lo; acc[9]  += g*hi;
      unpack2(yb.y, lo, hi); acc[10] += g*lo; acc[11] += g*hi;
      unpack2(yb.z, lo, hi); acc[12] += g*lo; acc[13] += g*hi;
      unpack2(yb.w, lo, hi); acc[14] += g*lo; acc[15] += g*hi;
    }
  }
#pragma unroll
  for (int s = 0; s < 16; s++) acc[s] *= INV_AVG;

  int ty = __builtin_amdgcn_readfirstlane(types[n]);
  const float* Ws = Wsc + (size_t)ty*4096;
  // node's own h row: layer 0 -> embedding row (h0 buffer eliminated)
  const float* hrow = (LAYER_KIND == 0) ? (wemb + ty*64) : (h_old + (size_t)n*64);
  float sc0 = 0.f, sc1 = 0.f, sc2 = 0.f, sc3 = 0.f;
#pragma unroll
  for (int c = 0; c < 64; c += 4){
    sc0 += hrow[c+0] * Ws[(c+0)*64 + lane];
    sc1 += hrow[c+1] * Ws[(c+1)*64 + lane];
    sc2 += hrow[c+2] * Ws[(c+2)*64 + lane];
    sc3 += hrow[c+3] * Ws[(c+3)*64 + lane];
  }
  float sc = (sc0 + sc1) + (sc2 + sc3);

  float inv0 = acc[0];
  float inv1 = acc[1]*acc[1] + acc[2]*acc[2] + acc[3]*acc[3];
  float inv2 = acc[4]*acc[4] + acc[5]*acc[5] + acc[6]*acc[6] + acc[7]*acc[7]
             + acc[8]*acc[8];
  float inv3 = acc[9]*acc[9] + acc[10]*acc[10] + acc[11]*acc[11] + acc[12]*acc[12]
             + acc[13]*acc[13] + acc[14]*acc[14] + acc[15]*acc[15];
  const float* wp = wprod + ty*4;
  float hn = inv0*wp[0] + inv1*wp[1] + inv2*wp[2] + inv3*wp[3] + sc;
  if (LAYER_KIND == 0)
    h_new[(size_t)n*64 + lane] = hn;   // layer-1 output is consumed in-kernel only

  float ev;
  if (LAYER_KIND == 0){
    float p = hn * wro0[lane];
#pragma unroll
    for (int off = 32; off >= 1; off >>= 1) p += __shfl_xor(p, off, 64);
    ev = p;
  } else {
    hn_l[lane] = hn;
    WSYNC();
    int j = lane & 15;
    float pj = 0.0f;
#pragma unroll
    for (int c = 0; c < 64; c++)
      pj += hn_l[c] * Wro1a[c*16 + j];
    float evj = silu_f(pj) * wro1b[j];
    evj += __shfl_xor(evj, 8, 64);
    evj += __shfl_xor(evj, 4, 64);
    evj += __shfl_xor(evj, 2, 64);
    evj += __shfl_xor(evj, 1, 64);
    ev = evj;
  }
  // contention-spread energy: consecutive nodes hit different copies
  if (lane == 0) atomicAdd(&ene2[(n & 7)*NGRP + batch[n]], ev);
}

// ---------------- final output: reduce ene2 copies + format convert ----------
__global__ void k_out(const float* __restrict__ ene2, const void* __restrict__ pos,
                      void* __restrict__ out){
  int fl = detect_fl(pos);
  int t = threadIdx.x;
  if (t < NGRP){
    float v = 0.0f;
#pragma unroll
    for (int k = 0; k < 8; k++) v += ene2[k*NGRP + t];
    if (fl) ((bf16*)out)[t] = __float2bfloat16(v);
    else    ((float*)out)[t] = v;
  }
}

static inline size_t rup(size_t x){ return (x + 255) & ~(size_t)255; }

extern "C" void kernel_launch(void* const* d_in, const int* in_sizes, int n_in,
                              void* d_out, int out_size, void* d_ws, size_t ws_size,
                              hipStream_t stream) {
  const void* pos   = d_in[0];
  const int*  types = (const int*)d_in[1];
  const int*  ei    = (const int*)d_in[2];
  const int*  batch = (const int*)d_in[3];
  const void* Wemb  = d_in[4];
  const void* Wr1   = d_in[5];
  const void* Wr2   = d_in[6];
  const void* Wr3   = d_in[7];
  const void* Wsc   = d_in[8];
  const void* wprod = d_in[9];
  const void* wro0  = d_in[10];
  const void* Wro1a = d_in[11];
  const void* wro1b = d_in[12];

  char* w = (char*)d_ws;
  float* cv       = (float*)w; w += rup((size_t)CVT_N*4);
  short* swz      = (short*)w; w += rup((size_t)SWZ_N*2);
  float* ene2     = (float*)w; w += 512;                      // 8 copies x 16
  int*   deg      = (int*)  w; w += rup((size_t)N_NODES*4);
  int*   row_start= (int*)  w; w += rup((size_t)(N_NODES+1)*4);
  int*   cursor   = (int*)  w; w += rup((size_t)N_NODES*4);
  int*   sslot    = (int*)  w; w += rup((size_t)N_EDGES*4);
  unsigned char* tsl = (unsigned char*)w; w += rup((size_t)N_EDGES);
  float* hbuf     = (float*)w; w += rup((size_t)N_NODES*64*4);
  float* rbuf     = (float*)w; w += rup((size_t)N_EDGES*4);
  unsigned short* Yb = (unsigned short*)w; w += rup((size_t)N_EDGES*16*2);
  w += 4096;   // DMA over-read slack (tail Y chunks read <=480B past Yb end)

  hipMemsetAsync(deg, 0, N_NODES*4, stream);

  const int* dstp = ei + N_EDGES;
  k_setup1<<<B_CVT + B_SWZ + B_HIST, 256, 0, stream>>>(
      pos, Wemb, Wsc, wprod, wro0, Wro1a, wro1b, Wr1, Wr2, Wr3, dstp, cv, swz, deg);
  k_scan<<<1, 1024, 0, stream>>>(deg, row_start, cursor, ene2);
  k_fillgeom<<<N_EDGES/256, 256, 0, stream>>>(ei, cursor, cv + CV_POS, types,
      sslot, tsl, Yb, rbuf);

  k_gu<0><<<N_NODES, 64, 0, stream>>>(swz, rbuf, tsl, sslot,
      hbuf /*unused*/, hbuf /*h_new*/, Yb, row_start, types,
      cv + CV_SC, cv + CV_PROD, cv + CV_EMB,
      cv + CV_RO0, cv + CV_RO1A, cv + CV_RO1B, batch, ene2);
  k_gu<1><<<N_NODES, 64, 0, stream>>>(swz + SWZ_PER_L, rbuf, tsl, sslot,
      hbuf /*h_old*/, hbuf /*unused*/, Yb, row_start, types,
      cv + CV_SC + (size_t)NELM*4096, cv + CV_PROD + NELM*4, cv + CV_EMB,
      cv + CV_RO0, cv + CV_RO1A, cv + CV_RO1B, batch, ene2);

  k_out<<<1, 64, 0, stream>>>(ene2, pos, d_out);
}

// Round 9
// 188.108 us; speedup vs baseline: 1.4084x; 1.0156x over previous
//
#include <hip/hip_runtime.h>
#include <hip/hip_bf16.h>
#include <math.h>

#define N_NODES 8192
#define N_EDGES 131072
#define NGRP 16
#define NLAY 2
#define NELM 4
constexpr float INV_AVG = 1.0f / 16.0f;
constexpr float PI_F = 3.14159265358979323846f;

// converted fp32 buffer layout (element offsets).
#define CV_POS   0        // 24576
#define CV_EMB   24576    // 256
#define CV_SC    42240    // 32768 (natural [l][ty][c:64][d:64])
#define CV_PROD  75008    // 32
#define CV_RO0   75040    // 64
#define CV_RO1A  75104    // 1024
#define CV_RO1B  76128    // 16
#define CVT_N    76144

// swizzled bf16 MFMA B-fragment weight buffer: per layer 10240 shorts
#define SWZ_PER_L 10240
#define SWZ_N     20480

// setup1 fused-dispatch block ranges
#define B_CVT  230
#define B_SWZ  80
#define B_HIST 512
#define CVT_WORK 58736

typedef __hip_bfloat16 bf16;
typedef __attribute__((ext_vector_type(8))) short bf16x8;
typedef __attribute__((ext_vector_type(4))) float f32x4;

__device__ __forceinline__ float silu_f(float x){ return x / (1.0f + __expf(-x)); }
__device__ __forceinline__ float bfbits2f(unsigned short u){
  return __uint_as_float(((unsigned)u) << 16);
}
__device__ __forceinline__ void unpack2(unsigned u, float& lo, float& hi){
  lo = __uint_as_float(u << 16);
  hi = __uint_as_float(u & 0xffff0000u);
}
__device__ __forceinline__ short f2bs(float v){
  union { bf16 b; short s; } u; u.b = __float2bfloat16(v); return u.s;
}
__device__ __forceinline__ float ldf(const void* p, int i, int flag){
  if (flag) return bfbits2f(((const unsigned short*)p)[i]);
  return ((const float*)p)[i];
}
// per-wave input dtype detection (reads first 128 ushorts of pos; L1/L2-hot).
__device__ __forceinline__ int detect_fl(const void* pos){
  int lane = threadIdx.x & 63;
  const unsigned short* u = (const unsigned short*)pos;
  float va = bfbits2f(u[2*lane]), vb = bfbits2f(u[2*lane+1]);
  bool bad = !(fabsf(va) <= 1000.0f) || !(fabsf(vb) <= 1000.0f);
  return (__ballot(bad) == 0ull) ? 1 : 0;
}
__device__ __forceinline__ void WSYNC(){ __builtin_amdgcn_wave_barrier(); }

// async global->LDS DMA: data never touches VGPRs. LDS dest wave-uniform,
// +lane*size implicit; global src per-lane.
__device__ __forceinline__ void gl_lds4(const void* g, void* l){
  __builtin_amdgcn_global_load_lds(
      (const __attribute__((address_space(1))) unsigned*)g,
      (__attribute__((address_space(3))) unsigned*)l, 4, 0, 0);
}

// ============ S1: fused {detect, cvt, weight-swizzle, degree-hist} ============
__global__ void k_setup1(const void* __restrict__ pos, const void* __restrict__ Wemb,
                         const void* __restrict__ Wsc, const void* __restrict__ wprod,
                         const void* __restrict__ wro0, const void* __restrict__ Wro1a,
                         const void* __restrict__ wro1b, const void* __restrict__ Wr1,
                         const void* __restrict__ Wr2, const void* __restrict__ Wr3,
                         const int* __restrict__ dstp, float* __restrict__ cv,
                         short* __restrict__ swz, int* __restrict__ deg){
  int b = blockIdx.x, tix = threadIdx.x;
  if (b >= B_CVT + B_SWZ){            // ---- degree histogram ----
    int e = (b - B_CVT - B_SWZ)*256 + tix;
    atomicAdd(&deg[dstp[e]], 1);
    return;
  }
  int fl = detect_fl(pos);
  if (b < B_CVT){                      // ---- fp32 conversion ----
    int i = b*256 + tix;
    if (i < 24576){ cv[CV_POS + i] = ldf(pos, i, fl); return; }
    if (i < 24832){ int j=i-24576; cv[CV_EMB + j] = ldf(Wemb, j, fl); return; }
    if (i < 57600){ int j=i-24832; cv[CV_SC  + j] = ldf(Wsc,  j, fl); return; }
    if (i < 57632){ int j=i-57600; cv[CV_PROD+ j] = ldf(wprod,j, fl); return; }
    if (i < 57696){ int j=i-57632; cv[CV_RO0 + j] = ldf(wro0, j, fl); return; }
    if (i < 58720){ int j=i-57696; cv[CV_RO1A+ j] = ldf(Wro1a,j, fl); return; }
    if (i < CVT_WORK){ int j=i-58720; cv[CV_RO1B+ j] = ldf(wro1b,j, fl); return; }
    return;
  }
  // ---- MFMA B-fragment-order bf16 weights, read directly from raw inputs ----
  int i = (b - B_CVT)*256 + tix;       // 20480 exact
  int l = i / SWZ_PER_L, w = i % SWZ_PER_L;
  float v;
  if (w < 2048){
    int t = w >> 9, q = (w >> 7) & 3, n = (w >> 3) & 15, j = w & 7;
    int k = q*8 + j;
    v = (k < 8) ? ldf(Wr1, l*512 + k*64 + t*16 + n, fl) : 0.0f;
  } else if (w < 6144){
    int w2 = w - 2048;
    int nt = w2 >> 10, kt = (w2 >> 9) & 1, q = (w2 >> 7) & 3, n = (w2 >> 3) & 15, j = w2 & 7;
    int k = kt*32 + q*8 + j;
    v = ldf(Wr2, l*4096 + k*64 + nt*16 + n, fl);
  } else {
    int w3 = w - 6144;
    int nt = w3 >> 10, kt = (w3 >> 9) & 1, q = (w3 >> 7) & 3, n = (w3 >> 3) & 15, j = w3 & 7;
    int k = kt*32 + q*8 + j;
    v = ldf(Wr3, l*4096 + k*64 + nt*16 + n, fl);
  }
  swz[i] = f2bs(v);
}

// ============ S2: prefix-scan + ene2-zero (1 block) ============
__global__ void k_scan(const int* __restrict__ deg, int* __restrict__ row_start,
                       int* __restrict__ cursor, float* __restrict__ ene2){
  __shared__ int lds[1024];
  int t = threadIdx.x;
  if (t < 8*NGRP) ene2[t] = 0.0f;
  int v[8]; int tot = 0;
#pragma unroll
  for (int k = 0; k < 8; k++){ v[k] = deg[t*8+k]; tot += v[k]; }
  lds[t] = tot; __syncthreads();
  for (int off = 1; off < 1024; off <<= 1){
    int x = (t >= off) ? lds[t-off] : 0;
    __syncthreads();
    lds[t] += x;
    __syncthreads();
  }
  int base = lds[t] - tot;
#pragma unroll
  for (int k = 0; k < 8; k++){ row_start[t*8+k] = base; cursor[t*8+k] = base; base += v[k]; }
  if (t == 1023) row_start[N_NODES] = base;
}

// ============ S3: fused {CSR fill, edge geometry, src-type} ============
__global__ void k_fillgeom(const int* __restrict__ ei, int* __restrict__ cursor,
                           const float* __restrict__ posf, const int* __restrict__ types,
                           int* __restrict__ sslot, unsigned char* __restrict__ tsl,
                           unsigned short* __restrict__ Yb, float* __restrict__ rbuf){
  int e = blockIdx.x*256 + threadIdx.x;
  int s = ei[e], d = ei[N_EDGES + e];
  int slot = atomicAdd(&cursor[d], 1);
  sslot[slot] = s;
  tsl[slot] = (unsigned char)types[s];
  float vx = posf[d*3+0] - posf[s*3+0];
  float vy = posf[d*3+1] - posf[s*3+1];
  float vz = posf[d*3+2] - posf[s*3+2];
  float r = sqrtf(vx*vx + vy*vy + vz*vz + 1e-12f);
  float ir = 1.0f / r;
  float x = vx*ir, y = vy*ir, z = vz*ir;
  const float s3 = 1.7320508075688772f, s15 = 3.872983346207417f, s5 = 2.23606797749979f;
  const float s105 = 10.246950765959598f, s7 = 2.6457513110645907f;
  const float c35 = 2.091650066335189f, c21 = 1.6201851746019651f;
  float x2 = x*x, y2 = y*y, z2 = z*z;
  float ys[16] = {
    1.0f, s3*x, s3*y, s3*z,
    s15*x*y, s15*y*z, 0.5f*s5*(3.0f*z2-1.0f), s15*x*z,
    0.5f*s15*(x2-y2), c35*y*(3.0f*x2-y2), s105*x*y*z, c21*y*(5.0f*z2-1.0f),
    0.5f*s7*(5.0f*z2*z-3.0f*z), c21*x*(5.0f*z2-1.0f), 0.5f*s105*z*(x2-y2),
    c35*x*(x2-3.0f*y2) };
  union { bf16 b[16]; uint4 u[2]; } pk;
#pragma unroll
  for (int k = 0; k < 16; k++) pk.b[k] = __float2bfloat16(ys[k]);
  uint4* yp = (uint4*)(Yb + (size_t)slot*16);
  yp[0] = pk.u[0];
  yp[1] = pk.u[1];
  rbuf[slot] = r;
}

// ====== fused node kernel, ONE WAVE PER BLOCK (node = blockIdx.x) ======
// Per 16-slot chunk: {Y(/h) DMA issue -> wave-private MFMA radial MLP (hides
// DMA) -> vmcnt(0) -> accumulate reading Rw straight from scratch A}.
// No __syncthreads anywhere; energy via contention-spread ene2[n&7][g].
// NOTE: no min-waves clamp in __launch_bounds__ -- R8's (64,4) capped VGPR
// at 64 (< ~88 live set) and spilled ~74MB/dispatch to scratch.
#define ROWS 72
template<int LAYER_KIND>
__global__ void __launch_bounds__(64) k_gu(const short* __restrict__ sw,
        const float* __restrict__ rbuf, const unsigned char* __restrict__ tsl,
        const int* __restrict__ sslot, const float* __restrict__ h_old,
        float* __restrict__ h_new, const unsigned short* __restrict__ Yb,
        const int* __restrict__ row_start, const int* __restrict__ types,
        const float* __restrict__ Wsc, const float* __restrict__ wprod,
        const float* __restrict__ wemb, const float* __restrict__ wro0,
        const float* __restrict__ Wro1a, const float* __restrict__ wro1b,
        const int* __restrict__ batch, float* __restrict__ ene2){
  __shared__ __align__(16) short A_[16*ROWS];                    // 2.25 KB
  __shared__ __align__(16) float hS[LAYER_KIND ? 16 : 1][64];    // 4 KB (L1)
  __shared__ __align__(16) unsigned short yS[16][16];            // 0.5 KB
  __shared__ float hn_l[64];
  int lane = threadIdx.x;
  int q = lane >> 4, nn = lane & 15;
  int n = blockIdx.x;
  int beg = row_start[n], end = row_start[n + 1];
  short* A = A_;

  const bf16x8* S1 = (const bf16x8*)(sw);
  const bf16x8* S2 = (const bf16x8*)(sw + 2048);
  const bf16x8* S3 = (const bf16x8*)(sw + 6144);

  // layer-0 embedding rows (4 types x 64 ch) in registers
  float e0=0.f, e1=0.f, e2=0.f, e3=0.f;
  if (LAYER_KIND == 0){
    e0 = wemb[lane]; e1 = wemb[64+lane]; e2 = wemb[128+lane]; e3 = wemb[192+lane];
  }

  float acc[16];
#pragma unroll
  for (int s = 0; s < 16; s++) acc[s] = 0.0f;

  for (int cb = beg; cb < end; cb += 16){
    int cnt = min(16, end - cb);
    WSYNC();   // fence: prior chunk's LDS reads precede this chunk's DMA/MLP
    // ---------- phase A: issue DMAs ----------
    const char* ysrc = (const char*)Yb + (size_t)cb*32 + lane*4;
    gl_lds4(ysrc,       &yS[0][0]);
    gl_lds4(ysrc + 256, &yS[8][0]);
    int tv = 0;
    if (LAYER_KIND == 0){
      tv = (int)tsl[min(cb + nn, N_EDGES - 1)];   // chunk types -> register
    } else {
      int sv = sslot[min(cb + nn, N_EDGES - 1)];
      for (int i = 0; i < cnt; i++){
        int src = __builtin_amdgcn_readlane(sv, i);
        gl_lds4(h_old + (size_t)src*64 + lane, &hS[i][0]);
      }
    }
    // ---------- phase B: wave-private MFMA radial MLP (hides DMA) ----------
    {
      float r = rbuf[min(cb + nn, N_EDGES - 1)];
      float xc = r * 0.2f;
      float f = 0.0f;
      if (xc < 1.0f){
        float x3 = xc*xc*xc, x6 = x3*x3, x7 = x6*xc, x8 = x7*xc;
        f = 1.0f - 28.0f*x6 + 48.0f*x7 - 21.0f*x8;
      }
      float bs = 0.6324555320336759f * f / r;
      float t0 = PI_F * r * 0.2f;
      bf16x8 af1 = {0,0,0,0,0,0,0,0};
      if (q == 0){
#pragma unroll
        for (int j = 0; j < 8; j++) af1[j] = f2bs(bs * __sinf((float)(j+1) * t0));
      }
      f32x4 macc[4];
#pragma unroll
      for (int t = 0; t < 4; t++){
        bf16x8 b = S1[t*64 + q*16 + nn];
        f32x4 z = {0.f,0.f,0.f,0.f};
        macc[t] = __builtin_amdgcn_mfma_f32_16x16x32_bf16(af1, b, z, 0, 0, 0);
      }
#pragma unroll
      for (int t = 0; t < 4; t++)
#pragma unroll
        for (int rg = 0; rg < 4; rg++)
          A[(q*4+rg)*ROWS + t*16 + nn] = f2bs(silu_f(macc[t][rg]));
      WSYNC();
      bf16x8 a0 = *(const bf16x8*)&A[nn*ROWS + 0*32 + q*8];
      bf16x8 a1 = *(const bf16x8*)&A[nn*ROWS + 1*32 + q*8];
      WSYNC();
#pragma unroll
      for (int t = 0; t < 4; t++){
        f32x4 z = {0.f,0.f,0.f,0.f};
        bf16x8 b0 = S2[t*128 + 0*64 + q*16 + nn];
        bf16x8 b1 = S2[t*128 + 1*64 + q*16 + nn];
        z = __builtin_amdgcn_mfma_f32_16x16x32_bf16(a0, b0, z, 0, 0, 0);
        z = __builtin_amdgcn_mfma_f32_16x16x32_bf16(a1, b1, z, 0, 0, 0);
        macc[t] = z;
      }
#pragma unroll
      for (int t = 0; t < 4; t++)
#pragma unroll
        for (int rg = 0; rg < 4; rg++)
          A[(q*4+rg)*ROWS + t*16 + nn] = f2bs(silu_f(macc[t][rg]));
      WSYNC();
      a0 = *(const bf16x8*)&A[nn*ROWS + 0*32 + q*8];
      a1 = *(const bf16x8*)&A[nn*ROWS + 1*32 + q*8];
      WSYNC();
#pragma unroll
      for (int t = 0; t < 4; t++){
        f32x4 z = {0.f,0.f,0.f,0.f};
        bf16x8 b0 = S3[t*128 + 0*64 + q*16 + nn];
        bf16x8 b1 = S3[t*128 + 1*64 + q*16 + nn];
        z = __builtin_amdgcn_mfma_f32_16x16x32_bf16(a0, b0, z, 0, 0, 0);
        z = __builtin_amdgcn_mfma_f32_16x16x32_bf16(a1, b1, z, 0, 0, 0);
        macc[t] = z;
      }
      // final Rw stays in A: layout A[slot*ROWS + ch]
#pragma unroll
      for (int t = 0; t < 4; t++)
#pragma unroll
        for (int rg = 0; rg < 4; rg++)
          A[(q*4+rg)*ROWS + t*16 + nn] = f2bs(macc[t][rg]);
      WSYNC();
    }
    // ---------- phase C: wait DMAs, accumulate (all wave-private) ----------
    asm volatile("s_waitcnt vmcnt(0)" ::: "memory");
    __builtin_amdgcn_sched_barrier(0);
    for (int i = 0; i < cnt; i++){
      float rw = bfbits2f((unsigned short)A[i*ROWS + lane]);  // 2-way alias: free
      float hv;
      if (LAYER_KIND == 0){
        int ty = __builtin_amdgcn_readlane(tv, i);
        hv = (ty & 2) ? ((ty & 1) ? e3 : e2) : ((ty & 1) ? e1 : e0);
      } else {
        hv = hS[i][lane];
      }
      float g = rw * hv;
      const uint4* yq = (const uint4*)&yS[i][0];   // uniform -> broadcast
      uint4 ya = yq[0], yb = yq[1];
      float lo, hi;
      unpack2(ya.x, lo, hi); acc[0]  += g*lo; acc[1]  += g*hi;
      unpack2(ya.y, lo, hi); acc[2]  += g*lo; acc[3]  += g*hi;
      unpack2(ya.z, lo, hi); acc[4]  += g*lo; acc[5]  += g*hi;
      unpack2(ya.w, lo, hi); acc[6]  += g*lo; acc[7]  += g*hi;
      unpack2(yb.x, lo, hi); acc[8]  += g*lo; acc[9]  += g*hi;
      unpack2(yb.y, lo, hi); acc[10] += g*lo; acc[11] += g*hi;
      unpack2(yb.z, lo, hi); acc[12] += g*lo; acc[13] += g*hi;
      unpack2(yb.w, lo, hi); acc[14] += g*lo; acc[15] += g*hi;
    }
  }
#pragma unroll
  for (int s = 0; s < 16; s++) acc[s] *= INV_AVG;

  int ty = __builtin_amdgcn_readfirstlane(types[n]);
  const float* Ws = Wsc + (size_t)ty*4096;
  // node's own h row: layer 0 -> embedding row (h0 buffer eliminated)
  const float* hrow = (LAYER_KIND == 0) ? (wemb + ty*64) : (h_old + (size_t)n*64);
  float sc0 = 0.f, sc1 = 0.f, sc2 = 0.f, sc3 = 0.f;
#pragma unroll
  for (int c = 0; c < 64; c += 4){
    sc0 += hrow[c+0] * Ws[(c+0)*64 + lane];
    sc1 += hrow[c+1] * Ws[(c+1)*64 + lane];
    sc2 += hrow[c+2] * Ws[(c+2)*64 + lane];
    sc3 += hrow[c+3] * Ws[(c+3)*64 + lane];
  }
  float sc = (sc0 + sc1) + (sc2 + sc3);

  float inv0 = acc[0];
  float inv1 = acc[1]*acc[1] + acc[2]*acc[2] + acc[3]*acc[3];
  float inv2 = acc[4]*acc[4] + acc[5]*acc[5] + acc[6]*acc[6] + acc[7]*acc[7]
             + acc[8]*acc[8];
  float inv3 = acc[9]*acc[9] + acc[10]*acc[10] + acc[11]*acc[11] + acc[12]*acc[12]
             + acc[13]*acc[13] + acc[14]*acc[14] + acc[15]*acc[15];
  const float* wp = wprod + ty*4;
  float hn = inv0*wp[0] + inv1*wp[1] + inv2*wp[2] + inv3*wp[3] + sc;
  if (LAYER_KIND == 0)
    h_new[(size_t)n*64 + lane] = hn;   // layer-1 output is consumed in-kernel only

  float ev;
  if (LAYER_KIND == 0){
    float p = hn * wro0[lane];
#pragma unroll
    for (int off = 32; off >= 1; off >>= 1) p += __shfl_xor(p, off, 64);
    ev = p;
  } else {
    hn_l[lane] = hn;
    WSYNC();
    int j = lane & 15;
    float pj = 0.0f;
#pragma unroll
    for (int c = 0; c < 64; c++)
      pj += hn_l[c] * Wro1a[c*16 + j];
    float evj = silu_f(pj) * wro1b[j];
    evj += __shfl_xor(evj, 8, 64);
    evj += __shfl_xor(evj, 4, 64);
    evj += __shfl_xor(evj, 2, 64);
    evj += __shfl_xor(evj, 1, 64);
    ev = evj;
  }
  // contention-spread energy: consecutive nodes hit different copies
  if (lane == 0) atomicAdd(&ene2[(n & 7)*NGRP + batch[n]], ev);
}

// ---------------- final output: reduce ene2 copies + format convert ----------
__global__ void k_out(const float* __restrict__ ene2, const void* __restrict__ pos,
                      void* __restrict__ out){
  int fl = detect_fl(pos);
  int t = threadIdx.x;
  if (t < NGRP){
    float v = 0.0f;
#pragma unroll
    for (int k = 0; k < 8; k++) v += ene2[k*NGRP + t];
    if (fl) ((bf16*)out)[t] = __float2bfloat16(v);
    else    ((float*)out)[t] = v;
  }
}

static inline size_t rup(size_t x){ return (x + 255) & ~(size_t)255; }

extern "C" void kernel_launch(void* const* d_in, const int* in_sizes, int n_in,
                              void* d_out, int out_size, void* d_ws, size_t ws_size,
                              hipStream_t stream) {
  const void* pos   = d_in[0];
  const int*  types = (const int*)d_in[1];
  const int*  ei    = (const int*)d_in[2];
  const int*  batch = (const int*)d_in[3];
  const void* Wemb  = d_in[4];
  const void* Wr1   = d_in[5];
  const void* Wr2   = d_in[6];
  const void* Wr3   = d_in[7];
  const void* Wsc   = d_in[8];
  const void* wprod = d_in[9];
  const void* wro0  = d_in[10];
  const void* Wro1a = d_in[11];
  const void* wro1b = d_in[12];

  char* w = (char*)d_ws;
  float* cv       = (float*)w; w += rup((size_t)CVT_N*4);
  short* swz      = (short*)w; w += rup((size_t)SWZ_N*2);
  float* ene2     = (float*)w; w += 512;                      // 8 copies x 16
  int*   deg      = (int*)  w; w += rup((size_t)N_NODES*4);
  int*   row_start= (int*)  w; w += rup((size_t)(N_NODES+1)*4);
  int*   cursor   = (int*)  w; w += rup((size_t)N_NODES*4);
  int*   sslot    = (int*)  w; w += rup((size_t)N_EDGES*4);
  unsigned char* tsl = (unsigned char*)w; w += rup((size_t)N_EDGES);
  float* hbuf     = (float*)w; w += rup((size_t)N_NODES*64*4);
  float* rbuf     = (float*)w; w += rup((size_t)N_EDGES*4);
  unsigned short* Yb = (unsigned short*)w; w += rup((size_t)N_EDGES*16*2);
  w += 4096;   // DMA over-read slack (tail Y chunks read <=480B past Yb end)

  hipMemsetAsync(deg, 0, N_NODES*4, stream);

  const int* dstp = ei + N_EDGES;
  k_setup1<<<B_CVT + B_SWZ + B_HIST, 256, 0, stream>>>(
      pos, Wemb, Wsc, wprod, wro0, Wro1a, wro1b, Wr1, Wr2, Wr3, dstp, cv, swz, deg);
  k_scan<<<1, 1024, 0, stream>>>(deg, row_start, cursor, ene2);
  k_fillgeom<<<N_EDGES/256, 256, 0, stream>>>(ei, cursor, cv + CV_POS, types,
      sslot, tsl, Yb, rbuf);

  k_gu<0><<<N_NODES, 64, 0, stream>>>(swz, rbuf, tsl, sslot,
      hbuf /*unused*/, hbuf /*h_new*/, Yb, row_start, types,
      cv + CV_SC, cv + CV_PROD, cv + CV_EMB,
      cv + CV_RO0, cv + CV_RO1A, cv + CV_RO1B, batch, ene2);
  k_gu<1><<<N_NODES, 64, 0, stream>>>(swz + SWZ_PER_L, rbuf, tsl, sslot,
      hbuf /*h_old*/, hbuf /*unused*/, Yb, row_start, types,
      cv + CV_SC + (size_t)NELM*4096, cv + CV_PROD + NELM*4, cv + CV_EMB,
      cv + CV_RO0, cv + CV_RO1A, cv + CV_RO1B, batch, ene2);

  k_out<<<1, 64, 0, stream>>>(ene2, pos, d_out);
}